// Round 11
// baseline (1063.694 us; speedup 1.0000x reference)
//
#include <hip/hip_runtime.h>

typedef unsigned short u16;
typedef unsigned int   u32;
typedef __attribute__((ext_vector_type(8))) short short8;   // 8 x bf16 (4 VGPRs)
typedef __attribute__((ext_vector_type(4))) float f32x4;    // MFMA accumulator

__device__ __forceinline__ float bf2f(u16 u){ return __uint_as_float(((u32)u)<<16); }
__device__ __forceinline__ u16 f2bf(float f){ u32 x = __float_as_uint(f); x += 0x7fffu + ((x>>16)&1u); return (u16)(x>>16); }
__device__ __forceinline__ float lrelu_f(float v){ return v >= 0.0f ? v : 0.01f*v; }

#if defined(__has_builtin)
#if __has_builtin(__builtin_amdgcn_global_load_lds)
#define HAS_GLL 1
#endif
#endif
#ifndef HAS_GLL
#define HAS_GLL 0
#endif

// async global->LDS DMA, 16B per lane; LDS dst = l + lane*16 (wave-uniform l).
// Defined unconditionally: host pass lacks the builtin (__has_builtin false on
// host target), so it gets a parse-only stub; device pass on gfx950 uses DMA.
__device__ __forceinline__ void gll16(const u16* g, u16* l){
#if HAS_GLL
  __builtin_amdgcn_global_load_lds(
      (__attribute__((address_space(1))) void*)(void*)g,
      (__attribute__((address_space(3))) void*)l, 16, 0, 0);
#else
  *(uint4*)l = *(const uint4*)g;   // never executed on gfx950; host-parse stub
#endif
}

// compiler-level memory fence around the HW barrier: prevents LDS/VMEM ops
// migrating across; MFMA/VALU may still move (harmless).
#define SBAR() { asm volatile("" ::: "memory"); __builtin_amdgcn_s_barrier(); asm volatile("" ::: "memory"); }
#define VMW(N) asm volatile("s_waitcnt vmcnt(" #N ")" ::: "memory")

// ---------------------------------------------------------------------------
// Implicit-GEMM conv (PROVEN r10/r12 config — conv0, i=1, MHA):
// Tile 128x128, BK=64, 4 waves x (4x4 of 16x16x32 bf16 MFMA), single acc,
// XOR-swizzled LDS, global_load_lds fast path, XCD-aware 1D grid decode.
// ---------------------------------------------------------------------------
template<bool PRED1, bool DUAL, bool F32OUT>
__global__ __launch_bounds__(256, 4) void gemm_conv(
    const u16* __restrict__ A1, const u16* __restrict__ B1,
    const u16* __restrict__ A2, const u16* __restrict__ B2,
    void* __restrict__ Out, const float* __restrict__ scale,
    const float* __restrict__ bias,
    int K1, int K2, int lgLo, int S1, int lgCin1, int P1, int Lin1,
    int Abatch1, int Arow1, int Abatch2, int Arow2,
    int Ncols, int Cout, int lrelu, int Mblks, int Nblks)
{
  __shared__ u16 ldsA[128*64];
  __shared__ u16 ldsB[128*64];
  const int tid = threadIdx.x;
  int nblk, mblk;
  {
    const int bid = blockIdx.x;
    if (Mblks & 7){ nblk = bid % Nblks; mblk = bid / Nblks; }
    else { const int grp = Nblks*8; const int g = bid/grp; const int r = bid - g*grp;
           nblk = r >> 3; mblk = g*8 + (r & 7); }
  }
  const int wv = tid >> 6, lane = tid & 63;
  const int mbase = (wv & 1)*64, nbase = (wv >> 1)*64;
  const int lq = lane >> 4, lm = lane & 15;
  const int sw = lm & 7;                            // fragment-read swizzle key

  f32x4 acc[4][4];
#pragma unroll
  for (int a_=0;a_<4;a_++)
#pragma unroll
    for (int b_=0;b_<4;b_++) acc[a_][b_] = (f32x4){0.f,0.f,0.f,0.f};

  float scv[4], biv[4];
  if constexpr (DUAL){
#pragma unroll
    for (int nt=0;nt<4;nt++){
      const int colg = nblk*128 + nbase + nt*16 + lm;   // DUAL: Ncols==Cout==256, in-range
      scv[nt] = scale[colg]; biv[nt] = bias[colg];
    }
  }

  auto mfma_step = [&](){
#pragma unroll
    for (int kk=0; kk<2; kk++){
      const int s8 = (((kk*4+lq) ^ sw) << 3);
      short8 af[4], bfr[4];
#pragma unroll
      for (int mt=0;mt<4;mt++) af[mt]  = *(const short8*)&ldsA[(mbase+mt*16+lm)*64 + s8];
#pragma unroll
      for (int nt=0;nt<4;nt++) bfr[nt] = *(const short8*)&ldsB[(nbase+nt*16+lm)*64 + s8];
#pragma unroll
      for (int mt=0;mt<4;mt++)
#pragma unroll
        for (int nt=0;nt<4;nt++)
          acc[mt][nt] = __builtin_amdgcn_mfma_f32_16x16x32_bf16(af[mt], bfr[nt], acc[mt][nt], 0,0,0);
    }
  };
  auto xform = [&](){                     // in-place epilogue at phase boundary
#pragma unroll
    for (int mt=0;mt<4;mt++)
#pragma unroll
      for (int nt=0;nt<4;nt++)
#pragma unroll
        for (int r=0;r<4;r++){
          float v = acc[mt][nt][r]*scv[nt] + biv[nt];
          acc[mt][nt][r] = lrelu ? lrelu_f(v) : v;
        }
  };

  const int Ktot = DUAL ? (K1 + K2) : K1;

  // wave-uniform interior test: unpredicated A reads for the whole m-tile?
  bool fast = (HAS_GLL != 0);
  if (PRED1 && fast){
    const int Lo = 1 << lgLo;
    if (Lo < 128) fast = false;
    else {
      const int lo0 = (mblk*128) & (Lo-1);
      const int taps = K1 >> lgCin1;
      fast = (lo0*S1 - P1 >= 0) && ((lo0+127)*S1 + taps - 1 - P1 < Lin1);
    }
  }

#if HAS_GLL
  if (fast){
    // Fast path: Lo>=128, tiles 128-aligned -> z constant per tile.
    const int pm0 = mblk*128;
    const int z0  = pm0 >> lgLo;
    const int lo0 = pm0 & ((1<<lgLo)-1);
    const int lr  = lane >> 3;
    const int lc8 = (lane & 7) ^ lr;              // swizzled chunk for this lane
    const u16* pA = A1 + (long)z0*Abatch1 + (long)(lo0 + wv*32 + lr)*Arow1 + lc8*8;
    const u16* pB = B1 + (long)(nblk*128 + wv*32 + lr)*K1 + lc8*8;
    long strA = Arow1, strB = K1;
    u16* da = &ldsA[(wv*32)*64];
    u16* db = &ldsB[(wv*32)*64];
    for (int k0 = 0; k0 < Ktot; k0 += 64){
      int kk = k0;
      if constexpr (DUAL){
        if (k0 >= K1){
          if (k0 == K1){
            pA = A2 + (long)z0*Abatch2 + (long)(lo0 + wv*32 + lr)*Arow2 + lc8*8;
            pB = B2 + (long)(nblk*128 + wv*32 + lr)*K2 + lc8*8;
            strA = Arow2; strB = K2;
          }
          kk = k0 - K1;
        }
      }
      __syncthreads();
#pragma unroll
      for (int u=0; u<4; u++) gll16(pA + (long)u*8*strA + kk, da + u*8*64);
#pragma unroll
      for (int u=0; u<4; u++) gll16(pB + (long)u*8*strB + kk, db + u*8*64);
      __syncthreads();      // drains DMA -> writes visible
      if constexpr (DUAL){ if (k0 == K1) xform(); }
      mfma_step();
    }
  } else
#endif
  {
    // predicated VGPR staging (zero-fills OOB taps), swizzled layout
    const int sr  = tid >> 1;
    const int cg  = (tid & 1)*4;
    const int pmS = mblk*128 + sr;
    const int zS  = pmS >> lgLo;
    const int loS = pmS & ((1<<lgLo)-1);
    const long aoff1 = (long)zS*Abatch1 + (long)loS*Arow1;
    long aoff2 = 0;
    if constexpr (DUAL) aoff2 = (long)zS*Abatch2 + (long)loS*Arow2;
    const int coS = nblk*128 + sr;
    const long boff1 = (long)coS*K1;
    long boff2 = 0;
    if constexpr (DUAL) boff2 = (long)coS*K2;
    const int ssw = sr & 7;

    for (int k0 = 0; k0 < Ktot; k0 += 64){
      const bool ph1 = !DUAL || (k0 < K1);
      __syncthreads();
      {
        const u16* asrc = ph1 ? (A1 + aoff1 + k0) : (A2 + aoff2 + (k0 - K1));
#pragma unroll
        for (int u=0; u<4; u++){
          const int c = cg + u;
          uint4 v; v.x=0u; v.y=0u; v.z=0u; v.w=0u;
          bool ok = true;
          if (PRED1 && ph1){
            int tap = (k0 + c*8) >> lgCin1;
            int pos = loS*S1 + tap - P1;
            ok = ((u32)pos < (u32)Lin1);
          }
          if (ok) v = *(const uint4*)(asrc + c*8);
          *(uint4*)&ldsA[sr*64 + ((c ^ ssw)*8)] = v;
        }
      }
      {
        const u16* bsrc = ph1 ? (B1 + boff1 + k0) : (B2 + boff2 + (k0 - K1));
#pragma unroll
        for (int u=0; u<4; u++){
          const int c = cg + u;
          uint4 v = *(const uint4*)(bsrc + c*8);
          *(uint4*)&ldsB[sr*64 + ((c ^ ssw)*8)] = v;
        }
      }
      __syncthreads();
      if constexpr (DUAL){ if (k0 == K1) xform(); }
      mfma_step();
    }
  }

  // epilogue: DUAL acc is already final (transform applied at boundary + id)
#pragma unroll
  for (int nt=0;nt<4;nt++){
    const int colg = nblk*128 + nbase + nt*16 + lm;
    if (colg >= Ncols) continue;
    float sc = 1.0f, bi = 0.0f;
    if constexpr (!DUAL){
      if (scale) sc = scale[colg];
      if (bias)  bi = bias[colg];
    }
#pragma unroll
    for (int mt=0;mt<4;mt++){
#pragma unroll
      for (int r=0;r<4;r++){
        const long pm = (long)mblk*128 + mbase + mt*16 + lq*4 + r;
        float v = acc[mt][nt][r];
        if constexpr (!DUAL){
          v = v*sc + bi;
          if (lrelu) v = lrelu_f(v);
        }
        if constexpr (F32OUT) ((float*)Out)[pm*Cout + colg] = v;
        else                  ((u16*)Out)[pm*Cout + colg] = f2bf(v);
      }
    }
  }
}

// ---------------------------------------------------------------------------
// r24: 64x128-tile sibling (gemm_sm) for deep layers i>=2, where the 128^2
// grids leave CUs idle (i=3: half, i=4: three-quarters). Same 2-barrier loop,
// same XOR-swizzle (row&7 == lm&7 on reads), same gll fast path / predicated
// fallback. 4 waves each own 64 rows x 32 cols (acc[4][2]); LDS 24 KiB.
// Grids double: i=2 512 blk (2/CU), i=3 256 (full), i=4 128. Extra B re-reads
// are L2-resident weights (~1.2 MB/layer).
// ---------------------------------------------------------------------------
template<bool PRED1, bool DUAL, bool F32OUT>
__global__ __launch_bounds__(256, 4) void gemm_sm(
    const u16* __restrict__ A1, const u16* __restrict__ B1,
    const u16* __restrict__ A2, const u16* __restrict__ B2,
    void* __restrict__ Out, const float* __restrict__ scale,
    const float* __restrict__ bias,
    int K1, int K2, int lgLo, int S1, int lgCin1, int P1, int Lin1,
    int Abatch1, int Arow1, int Abatch2, int Arow2,
    int Ncols, int Cout, int lrelu, int Mblks, int Nblks)
{
  __shared__ u16 ldsA[64*64];
  __shared__ u16 ldsB[128*64];
  const int tid = threadIdx.x;
  int nblk, mblk;
  {
    const int bid = blockIdx.x;
    if (Mblks & 7){ nblk = bid % Nblks; mblk = bid / Nblks; }
    else { const int grp = Nblks*8; const int g = bid/grp; const int r = bid - g*grp;
           nblk = r >> 3; mblk = g*8 + (r & 7); }
  }
  const int wv = tid >> 6, lane = tid & 63;
  const int lq = lane >> 4, lm = lane & 15;
  const int sw = lm & 7;

  f32x4 acc[4][2];
#pragma unroll
  for (int a_=0;a_<4;a_++)
#pragma unroll
    for (int b_=0;b_<2;b_++) acc[a_][b_] = (f32x4){0.f,0.f,0.f,0.f};

  float scv[2], biv[2];
  if constexpr (DUAL){
#pragma unroll
    for (int nt=0;nt<2;nt++){
      const int colg = nblk*128 + wv*32 + nt*16 + lm;
      scv[nt] = scale[colg]; biv[nt] = bias[colg];
    }
  }

  auto mfma_step = [&](){
#pragma unroll
    for (int kk=0; kk<2; kk++){
      const int s8 = (((kk*4+lq) ^ sw) << 3);
      short8 af[4], bfr[2];
#pragma unroll
      for (int mt=0;mt<4;mt++) af[mt]  = *(const short8*)&ldsA[(mt*16+lm)*64 + s8];
#pragma unroll
      for (int nt=0;nt<2;nt++) bfr[nt] = *(const short8*)&ldsB[(wv*32+nt*16+lm)*64 + s8];
#pragma unroll
      for (int mt=0;mt<4;mt++)
#pragma unroll
        for (int nt=0;nt<2;nt++)
          acc[mt][nt] = __builtin_amdgcn_mfma_f32_16x16x32_bf16(af[mt], bfr[nt], acc[mt][nt], 0,0,0);
    }
  };
  auto xform = [&](){
#pragma unroll
    for (int mt=0;mt<4;mt++)
#pragma unroll
      for (int nt=0;nt<2;nt++)
#pragma unroll
        for (int r=0;r<4;r++){
          float v = acc[mt][nt][r]*scv[nt] + biv[nt];
          acc[mt][nt][r] = lrelu ? lrelu_f(v) : v;
        }
  };

  const int Ktot = DUAL ? (K1 + K2) : K1;

  // wave-uniform interior test for the 64-row m-tile
  bool fast = (HAS_GLL != 0);
  if (PRED1 && fast){
    const int Lo = 1 << lgLo;
    if (Lo < 64) fast = false;
    else {
      const int lo0 = (mblk*64) & (Lo-1);
      const int taps = K1 >> lgCin1;
      fast = (lo0*S1 - P1 >= 0) && ((lo0+63)*S1 + taps - 1 - P1 < Lin1);
    }
  }

#if HAS_GLL
  if (fast){
    const int pm0 = mblk*64;
    const int z0  = pm0 >> lgLo;
    const int lo0 = pm0 & ((1<<lgLo)-1);
    const int lr  = lane >> 3;
    const int lc8 = (lane & 7) ^ lr;              // swizzled chunk (row&7 == lr)
    const u16* pA = A1 + (long)z0*Abatch1 + (long)(lo0 + wv*16 + lr)*Arow1 + lc8*8;
    const u16* pB = B1 + (long)(nblk*128 + wv*32 + lr)*K1 + lc8*8;
    long strA = Arow1, strB = K1;
    u16* da = &ldsA[(wv*16)*64];
    u16* db = &ldsB[(wv*32)*64];
    for (int k0 = 0; k0 < Ktot; k0 += 64){
      int kk = k0;
      if constexpr (DUAL){
        if (k0 >= K1){
          if (k0 == K1){
            pA = A2 + (long)z0*Abatch2 + (long)(lo0 + wv*16 + lr)*Arow2 + lc8*8;
            pB = B2 + (long)(nblk*128 + wv*32 + lr)*K2 + lc8*8;
            strA = Arow2; strB = K2;
          }
          kk = k0 - K1;
        }
      }
      __syncthreads();
#pragma unroll
      for (int u=0; u<2; u++) gll16(pA + (long)u*8*strA + kk, da + u*8*64);
#pragma unroll
      for (int u=0; u<4; u++) gll16(pB + (long)u*8*strB + kk, db + u*8*64);
      __syncthreads();
      if constexpr (DUAL){ if (k0 == K1) xform(); }
      mfma_step();
    }
  } else
#endif
  {
    // predicated VGPR staging: A 64 rows (4 thr/row x 2 chunks), B 128 rows
    const int srA = tid >> 2;                    // 0..63
    const int cgA = (tid & 3)*2;                 // 0,2,4,6
    const int pmS = mblk*64 + srA;
    const int zS  = pmS >> lgLo;
    const int loS = pmS & ((1<<lgLo)-1);
    const long aoff1 = (long)zS*Abatch1 + (long)loS*Arow1;
    long aoff2 = 0;
    if constexpr (DUAL) aoff2 = (long)zS*Abatch2 + (long)loS*Arow2;
    const int sswA = srA & 7;
    const int srB = tid >> 1;                    // 0..127
    const int cgB = (tid & 1)*4;
    const int coS = nblk*128 + srB;
    const long boff1 = (long)coS*K1;
    long boff2 = 0;
    if constexpr (DUAL) boff2 = (long)coS*K2;
    const int sswB = srB & 7;

    for (int k0 = 0; k0 < Ktot; k0 += 64){
      const bool ph1 = !DUAL || (k0 < K1);
      __syncthreads();
      {
        const u16* asrc = ph1 ? (A1 + aoff1 + k0) : (A2 + aoff2 + (k0 - K1));
#pragma unroll
        for (int u=0; u<2; u++){
          const int c = cgA + u;
          uint4 v; v.x=0u; v.y=0u; v.z=0u; v.w=0u;
          bool ok = true;
          if (PRED1 && ph1){
            int tap = (k0 + c*8) >> lgCin1;
            int pos = loS*S1 + tap - P1;
            ok = ((u32)pos < (u32)Lin1);
          }
          if (ok) v = *(const uint4*)(asrc + c*8);
          *(uint4*)&ldsA[srA*64 + ((c ^ sswA)*8)] = v;
        }
      }
      {
        const u16* bsrc = ph1 ? (B1 + boff1 + k0) : (B2 + boff2 + (k0 - K1));
#pragma unroll
        for (int u=0; u<4; u++){
          const int c = cgB + u;
          uint4 v = *(const uint4*)(bsrc + c*8);
          *(uint4*)&ldsB[srB*64 + ((c ^ sswB)*8)] = v;
        }
      }
      __syncthreads();
      if constexpr (DUAL){ if (k0 == K1) xform(); }
      mfma_step();
    }
  }

#pragma unroll
  for (int nt=0;nt<2;nt++){
    const int colg = nblk*128 + wv*32 + nt*16 + lm;
    if (colg >= Ncols) continue;
    float sc = 1.0f, bi = 0.0f;
    if constexpr (!DUAL){
      if (scale) sc = scale[colg];
      if (bias)  bi = bias[colg];
    }
#pragma unroll
    for (int mt=0;mt<4;mt++){
#pragma unroll
      for (int r=0;r<4;r++){
        const long pm = (long)mblk*64 + mt*16 + lq*4 + r;
        float v = acc[mt][nt][r];
        if constexpr (!DUAL){
          v = v*sc + bi;
          if (lrelu) v = lrelu_f(v);
        }
        if constexpr (F32OUT) ((float*)Out)[pm*Cout + colg] = v;
        else                  ((u16*)Out)[pm*Cout + colg] = f2bf(v);
      }
    }
  }
}

// ---------------------------------------------------------------------------
// r21/r22/r23: 256x256 engine, two-barrier deep-prefetch KTILE (measured-best).
// Engine placement (measured): gemm8 ONLY for i=0; gemm_conv for conv0, i=1,
// MHA; gemm_sm (r24) for i>=2. gemm8 structure iteration CLOSED.
// ---------------------------------------------------------------------------
#define RDA(BUF, MH) {                                                     \
  _Pragma("unroll") for (int mt=0; mt<4; mt++)                             \
  _Pragma("unroll") for (int kk=0; kk<2; kk++)                             \
    Ar[mt][kk] = *(const short8*)&ldsA[BUF][(((wr<<7) + (((MH)*4+mt)<<4) + lm)<<6) + (((kk*4+lq)^sw)<<3)]; }
#define RDB(BUF, NH, RB) {                                                 \
  _Pragma("unroll") for (int nt=0; nt<2; nt++)                             \
  _Pragma("unroll") for (int kk=0; kk<2; kk++)                             \
    RB[nt][kk] = *(const short8*)&ldsB[BUF][(((wc<<6) + (((NH)*2+nt)<<4) + lm)<<6) + (((kk*4+lq)^sw)<<3)]; }
#define MME(MH, NH, RB) {                                                  \
  __builtin_amdgcn_s_setprio(1);                                           \
  _Pragma("unroll") for (int mt=0; mt<4; mt++)                             \
  _Pragma("unroll") for (int nt=0; nt<2; nt++)                             \
  _Pragma("unroll") for (int kk=0; kk<2; kk++)                             \
    acc[(MH)*4+mt][(NH)*2+nt] = __builtin_amdgcn_mfma_f32_16x16x32_bf16(   \
        Ar[mt][kk], RB[nt][kk], acc[(MH)*4+mt][(NH)*2+nt], 0,0,0);         \
  __builtin_amdgcn_s_setprio(0); }

// One K-tile = 4 phases. Stages target tile G+2 (same BUF), each slot staged
// immediately after its last ds_read retired (enforced by the barrier pair of
// the phase where it was read). vmcnt(8) at P4 = tile G+1 fully landed (its 8
// loads were issued in iteration G-1, >=4 phases ago); in-flight = tile G+2.
#define KTILE(G, BUF) {                                                    \
  if constexpr (DUAL){ if ((G) == t1) xf(); }                              \
  /* P1: A-ev + B-ev of tile G */                                          \
  RDA(BUF, 0); RDB(BUF, 0, Br0);                                           \
  SBAR(); MME(0,0,Br0); SBAR();                                            \
  /* P2: B-od of tile G; stage A-ev(G+2) (slot freed by P1 barrier) */     \
  RDB(BUF, 1, Br1);                                                        \
  if ((G)+2 < nT) stA((G)+2, 0);                                           \
  SBAR(); MME(0,1,Br1); SBAR();                                            \
  /* P3: A-od of tile G; stage B-ev+B-od(G+2) (freed P1/P2) */             \
  RDA(BUF, 1);                                                             \
  if ((G)+2 < nT){ stB((G)+2, 0); stB((G)+2, 1); }                         \
  SBAR(); MME(1,0,Br0); SBAR();                                            \
  /* P4: stage A-od(G+2) (freed P3); counted wait for tile G+1 */          \
  if ((G)+2 < nT) stA((G)+2, 1);                                           \
  SBAR(); MME(1,1,Br1);                                                    \
  if ((G)+2 < nT) { VMW(8); } else { VMW(0); }                             \
  SBAR(); }

template<bool DUAL>
__global__ __launch_bounds__(512, 2) void gemm8(
    const u16* __restrict__ A1, const u16* __restrict__ B1,
    const u16* __restrict__ A2, const u16* __restrict__ B2,
    u16* __restrict__ Out, const float* __restrict__ scale,
    const float* __restrict__ bias, const u16* __restrict__ zb,
    int K1, int K2, int lgLo, int S1, int lgCin1, int P1, int Lin1,
    int Abatch1, int Arow1, int Abatch2, int Arow2)
{
  __shared__ u16 ldsA[2][16384];     // [buf][256 rows][64]
  __shared__ u16 ldsB[2][16384];

  const int tid  = threadIdx.x;
  const int wv   = tid >> 6, lane = tid & 63;
  const int wr   = wv >> 2, wc = wv & 3;
  const int lq   = lane >> 4, lm = lane & 15, sw = lm & 7;
  const int lr   = lane >> 3;
  const int cG   = (lane & 7) ^ lr;                 // pre-swizzled global chunk

  const int pm0 = blockIdx.x << 8;
  const int z0  = pm0 >> lgLo;
  const int lo0 = pm0 & ((1 << lgLo) - 1);

  const u16* baA1 = A1 + (long)z0*Abatch1 + (long)(lo0 + lr)*Arow1 + cG*8;
  const u16* baB1 = B1 + (long)lr*K1 + cG*8;
  const u16* baA2 = nullptr; const u16* baB2 = nullptr;
  if constexpr (DUAL){
    baA2 = A2 + (long)z0*Abatch2 + (long)(lo0 + lr)*Arow2 + cG*8;
    baB2 = B2 + (long)lr*K2 + cG*8;
  }
  const int posL = (lo0 + lr)*S1 - P1;              // per-lane pos base
  const int nT = (DUAL ? (K1 + K2) : K1) >> 6;
  const int t1 = DUAL ? (K1 >> 6) : 0x7fffffff;

  // block-uniform: no A tap can fall outside [0, Lin1) for this m-tile?
  bool interior;
  {
    const int taps = K1 >> lgCin1;
    interior = (lo0*S1 - P1 >= 0) && ((lo0+255)*S1 + taps - 1 - P1 < Lin1);
  }

  f32x4 acc[8][4];
#pragma unroll
  for (int a_=0;a_<8;a_++)
#pragma unroll
    for (int b_=0;b_<4;b_++) acc[a_][b_] = (f32x4){0.f,0.f,0.f,0.f};

  float scv[4], biv[4];
  if constexpr (DUAL){
#pragma unroll
    for (int nt=0;nt<4;nt++){
      const int colg = (wc<<6) + (nt<<4) + lm;
      scv[nt] = scale[colg]; biv[nt] = bias[colg];
    }
  }
  auto xf = [&](){                 // DUAL boundary transform (bn+lrelu on conv part)
#pragma unroll
    for (int mt=0;mt<8;mt++)
#pragma unroll
      for (int nt=0;nt<4;nt++)
#pragma unroll
        for (int r=0;r<4;r++){
          float v = acc[mt][nt][r]*scv[nt] + biv[nt];
          acc[mt][nt][r] = lrelu_f(v);
        }
  };

  // stage one A quarter-pair unit (16KiB, 2 gll/thread) of K-tile tau
  auto stA = [&](int tau, int odd){
    u16* dbase = &ldsA[tau & 1][0];
#pragma unroll
    for (int u=0; u<2; u++){
      const int riu = (wv<<4) + (u<<3);                       // 0..120, wave-uniform
      const int rl  = riu + (odd<<6) + ((riu >= 64) ? 64 : 0);// LDS/global row base
      u16* dst = dbase + (rl<<6);
      if (tau < t1){
        const int kloc = tau << 6;
        const u16* src = baA1 + (long)rl*Arow1 + kloc;
        if (!interior){
          const int tap = (kloc + cG*8) >> lgCin1;
          const int pos = posL + rl*S1 + tap;
          if ((u32)pos >= (u32)Lin1) src = zb;                // per-lane zero-page clamp
        }
        gll16(src, dst);
      } else {
        const int kloc = (tau << 6) - K1;                     // identity path: never OOB
        gll16(baA2 + (long)rl*Arow2 + kloc, dst);
      }
    }
  };
  // stage one B quarter-pair unit
  auto stB = [&](int tau, int odd){
    u16* dbase = &ldsB[tau & 1][0];
#pragma unroll
    for (int u=0; u<2; u++){
      const int riu = (wv<<4) + (u<<3);
      const int cl  = (riu & 31) + ((riu >> 5) << 6) + (odd << 5);
      u16* dst = dbase + (cl<<6);
      if (tau < t1) gll16(baB1 + (long)cl*K1 + (tau<<6), dst);
      else          gll16(baB2 + (long)cl*K2 + ((tau<<6) - K1), dst);
    }
  };

  short8 Ar[4][2], Br0[2][2], Br1[2][2];

  // prologue: tiles 0 and 1 fully staged -> vmcnt(8) = tile0 landed (tile1 in flight)
  stA(0,0); stA(0,1); stB(0,0); stB(0,1);
  if (nT > 1){ stA(1,0); stA(1,1); stB(1,0); stB(1,1); }
  VMW(8); SBAR();

  for (int g2 = 0; g2 < nT; g2 += 2){     // nT even
    KTILE(g2,   0);
    KTILE(g2+1, 1);
  }
  asm volatile("s_waitcnt vmcnt(0)" ::: "memory");

  // epilogue (Cout==256): non-DUAL applies bn+lrelu; DUAL acc already final
#pragma unroll
  for (int nt=0; nt<4; nt++){
    const int colg = (wc<<6) + (nt<<4) + lm;
    float sc = 1.0f, bi = 0.0f;
    if constexpr (!DUAL){ sc = scale[colg]; bi = bias[colg]; }
#pragma unroll
    for (int mt=0; mt<8; mt++){
#pragma unroll
      for (int r=0; r<4; r++){
        const long pm = (long)pm0 + (wr<<7) + (mt<<4) + (lq<<2) + r;
        float v = acc[mt][nt][r];
        if constexpr (!DUAL) v = lrelu_f(v*sc + bi);
        Out[pm*256 + colg] = f2bf(v);
      }
    }
  }
}

#undef RDA
#undef RDB
#undef MME
#undef KTILE

// --------------------------- prep kernels (fp32 -> bf16) --------------------
__global__ void bnfold_kernel(
    const float* __restrict__ bn0, const float* __restrict__ rbn1, const float* __restrict__ rbn2,
    float* s0, float* b0, float* s1, float* b1, float* s2, float* b2)
{
  const int blk = blockIdx.x, t = threadIdx.x;   // t < 256
  const float* p; float *so, *bo;
  if (blk == 0){ p = bn0; so = s0; bo = b0; }
  else if (blk <= 5){ int i = blk-1; p = rbn1 + i*1024; so = s1+i*256; bo = b1+i*256; }
  else { int i = blk-6; p = rbn2 + i*1024; so = s2+i*256; bo = b2+i*256; }
  const float g = p[t], be = p[256+t], m = p[512+t], v = p[768+t];
  const float sc = g / sqrtf(v + 1e-5f);
  so[t] = sc; bo[t] = be - m*sc;
}

__global__ void w0prep_kernel(const float* __restrict__ cw, u16* __restrict__ w0p){
  const int co = blockIdx.x, k = threadIdx.x;
  const int tp = k >> 4, ci = k & 15;
  u16 v = 0;
  if (tp < 15 && ci < 12) v = f2bf(cw[(co*12 + ci)*15 + tp]);
  w0p[co*256 + k] = v;
}

// coalesced: threads walk the 2304-elem source row contiguously
__global__ void wrprep_kernel(const float* __restrict__ c1, const float* __restrict__ c2, u16* __restrict__ wr){
  const int co = blockIdx.x, slot = blockIdx.y;
  const float* src = (slot < 5) ? (c1 + (size_t)slot*589824 + (size_t)co*2304)
                                : (c2 + (size_t)(slot-5)*589824 + (size_t)co*2304);
  u16* dst = wr + (size_t)slot*589824 + (size_t)co*2304;
  for (int k = threadIdx.x; k < 2304; k += 256){
    const int ci = k/9, tp = k - ci*9;
    dst[tp*256 + ci] = f2bf(src[k]);
  }
}

__global__ void widprep_kernel(const float* __restrict__ idw, u16* __restrict__ wid){
  const int co = blockIdx.x, sl = blockIdx.y, ci = threadIdx.x;
  u16 h = f2bf(0.5f * idw[((size_t)sl*256 + co)*256 + ci]);
  u16* dst = wid + (size_t)sl*131072 + co*512;
  dst[ci] = h; dst[256 + ci] = h;
}

__global__ void x16prep_kernel(const float* __restrict__ x, u16* __restrict__ x16){
  const int p = blockIdx.x*256 + threadIdx.x;
  const int b = blockIdx.y;
  u16 v[16];
#pragma unroll
  for (int ci=0; ci<16; ci++) v[ci] = (ci < 12) ? f2bf(x[((size_t)(b*12+ci))*4096 + p]) : (u16)0;
  uint4 A4, B4;
  A4.x = v[0] | ((u32)v[1]<<16); A4.y = v[2] | ((u32)v[3]<<16);
  A4.z = v[4] | ((u32)v[5]<<16); A4.w = v[6] | ((u32)v[7]<<16);
  B4.x = v[8] | ((u32)v[9]<<16); B4.y = v[10]| ((u32)v[11]<<16);
  B4.z = v[12]| ((u32)v[13]<<16); B4.w = v[14]| ((u32)v[15]<<16);
  uint4* dst = (uint4*)&x16[((size_t)b*4096 + p)*16];
  dst[0] = A4; dst[1] = B4;
}

// generic fp32 -> bf16 cast
__global__ void castb_kernel(const float* __restrict__ src, u16* __restrict__ dst, int n){
  const int i = blockIdx.x*256 + threadIdx.x;
  if (i < n) dst[i] = f2bf(src[i]);
}

__global__ void zerok_kernel(u16* __restrict__ zb){ zb[threadIdx.x] = 0; }

__global__ void canary_kernel(float* __restrict__ outp){
  const int idx = blockIdx.x*256 + threadIdx.x;
  if (idx < 3456) outp[idx] = 131072.0f;
}

// --------------------------- fp32 kernels -----------------------------------
// r18: fused lead-II branch. One kernel does BOTH convs (flut k=15 s=2 p=7,
// pvc k=9 s=2 p=4) + bn + lrelu + both max-pools, never materializing the
// (64,64,2048) activations (saves ~134 MB of fp32 traffic + 3 launches).
__global__ __launch_bounds__(256) void leadii_fused(
    const float* __restrict__ x,
    const float* __restrict__ fwg, const float* __restrict__ fbc, const float* __restrict__ fbn,
    const float* __restrict__ pwg, const float* __restrict__ pbc, const float* __restrict__ pbn,
    float* __restrict__ fp, float* __restrict__ pp)
{
  __shared__ float ldin[1040];
  const int opart = blockIdx.x;            // output chunk [opart*512, +512)
  const int z     = blockIdx.y;
  const int t = threadIdx.x;
  const float* xrow = x + ((size_t)(z*12 + 1))*4096;
  const int lo_in = opart*1024 - 7;        // ldin[i] = xrow[lo_in + i]
  for (int i = t; i < 1037; i += 256){
    const int pos = lo_in + i;
    ldin[i] = ((u32)pos < 4096u) ? xrow[pos] : 0.f;
  }
  __syncthreads();
  const int q = t >> 6, c = t & 63;
  float fw[15], pw[9];
#pragma unroll
  for (int k = 0; k < 15; k++) fw[k] = fwg[c*15 + k];
#pragma unroll
  for (int k = 0; k < 9;  k++) pw[k] = pwg[c*9 + k];
  const float fsc = fbn[c] / sqrtf(fbn[192+c] + 1e-5f);
  const float fsh = fbn[64+c] - fbn[128+c]*fsc;
  const float psc = pbn[c] / sqrtf(pbn[192+c] + 1e-5f);
  const float psh = pbn[64+c] - pbn[128+c]*psc;
  const float cbf = fbc[c], cbp = pbc[c];
  const int ob = q*128;                    // local output base for this thread
#pragma unroll
  for (int jp = 0; jp < 2; jp++){
    float pmx = -1e30f;
#pragma unroll
    for (int jf = 0; jf < 2; jf++){
      float fmx = -1e30f;
      for (int kk = 0; kk < 32; kk++){
        const int o = ob + jp*64 + jf*32 + kk;
        const float* s = &ldin[2*o];       // flut taps s[0..14]; pvc taps s[3..11]
        float fa = cbf;
#pragma unroll
        for (int k = 0; k < 15; k++) fa += fw[k]*s[k];
        fmx = fmaxf(fmx, lrelu_f(fa*fsc + fsh));
        float pa = cbp;
#pragma unroll
        for (int k = 0; k < 9;  k++) pa += pw[k]*s[3+k];
        pmx = fmaxf(pmx, lrelu_f(pa*psc + psh));
      }
      fp[(size_t)z*4096 + c*64 + opart*16 + q*4 + jp*2 + jf] = fmx;
    }
    pp[(size_t)z*2048 + c*32 + opart*8 + q*2 + jp] = pmx;
  }
}

// attention v3: one wave per (sample, head); K,V staged in LDS.
// qkv rows (64*nb, 768) fp32 -> o (64*nb, 256) bf16
__global__ __launch_bounds__(64) void attn3(const float* __restrict__ qkv, u16* __restrict__ o){
  const int bh = blockIdx.x;
  const int b = bh >> 3, h = bh & 7;
  __shared__ float Ks[2048], Vs[2048];
  const int t = threadIdx.x;
  for (int e = t; e < 2048; e += 64){
    const int r = e >> 5, c = e & 31;
    const size_t base = ((size_t)(b*64 + r))*768 + h*32 + c;
    Ks[e] = qkv[base + 256];
    Vs[e] = qkv[base + 512];
  }
  __syncthreads();
  float qv[32];
  const float* qp = qkv + ((size_t)(b*64 + t))*768 + h*32;
#pragma unroll
  for (int d = 0; d < 32; d++) qv[d] = qp[d];
  float s[64]; float mx = -1e30f;
  const float isq = 0.17677669529663687f;        // 1/sqrt(32)
  for (int kc = 0; kc < 64; kc++){
    const float* kr = &Ks[kc*32];
    float dot = 0.f;
#pragma unroll
    for (int d = 0; d < 32; d++) dot += qv[d]*kr[d];
    dot *= isq; s[kc] = dot; mx = fmaxf(mx, dot);
  }
  float sum = 0.f;
  for (int kc = 0; kc < 64; kc++){ float e = __expf(s[kc]-mx); s[kc] = e; sum += e; }
  const float inv = 1.0f/sum;
  float ov[32];
#pragma unroll
  for (int d = 0; d < 32; d++) ov[d] = 0.f;
  for (int kc = 0; kc < 64; kc++){
    const float* vr = &Vs[kc*32];
    const float wgt = s[kc];
#pragma unroll
    for (int d = 0; d < 32; d++) ov[d] += wgt*vr[d];
  }
  u16* op = o + ((size_t)(b*64 + t))*256 + h*32;
#pragma unroll
  for (int d = 0; d < 32; d++) op[d] = f2bf(ov[d]*inv);
}

__global__ void xmain_s(const float* __restrict__ om, float* __restrict__ xm, int b0){
  const int e = threadIdx.x, bl = blockIdx.x;
  float m = -1e30f;
  for (int s = 0; s < 64; s++) m = fmaxf(m, om[((size_t)(bl*64+s))*256 + e]);
  xm[(size_t)(b0+bl)*256 + e] = m;
}

// FC dot-product: one block per output scalar (b,j); float4 K-reduction.
template<int N, int K>
__global__ __launch_bounds__(256) void fcdot_kernel(const float* __restrict__ inp,
    const float* __restrict__ w, float* __restrict__ outp)
{
  const int b = blockIdx.x, j = blockIdx.y;
  const int t = threadIdx.x;
  const float4* x4 = (const float4*)(inp + (size_t)b*K);
  const float4* w4 = (const float4*)(w   + (size_t)j*K);
  float s = 0.f;
#pragma unroll
  for (int k = t; k < K/4; k += 256){
    const float4 a = x4[k], c = w4[k];
    s += a.x*c.x + a.y*c.y + a.z*c.z + a.w*c.w;
  }
  for (int o2 = 32; o2 > 0; o2 >>= 1) s += __shfl_down(s, o2, 64);
  __shared__ float red[4];
  const int wv = t >> 6, lane = t & 63;
  if (lane == 0) red[wv] = s;
  __syncthreads();
  if (t == 0) outp[(size_t)b*N + j] = lrelu_f(red[0]+red[1]+red[2]+red[3]);
}

// r18 DFT v2: block = (b, 8-bin chunk); row staged once in LDS; 8 lanes/bin
// with interleaved n-assignment (n = k*8+sub -> conflict-free, 8-way bcast);
// twiddle rotation recurrence; shfl_xor reduce within 8-lane groups.
__global__ __launch_bounds__(256) void fft2_kernel(const float* __restrict__ x, float* __restrict__ mag){
  __shared__ float row[4096];
  const int b = blockIdx.x, chunk = blockIdx.y;
  const int t = threadIdx.x;
  const float* xp = x + ((size_t)(b*12 + 1))*4096;
  for (int i = t; i < 4096; i += 256) row[i] = xp[i];
  __syncthreads();
  const int binl = t >> 3, sub = t & 7;
  const int bin = chunk*32 + binl + 50;
  const float C = 6.283185307179586f/4096.0f;
  float cr, si;  __sincosf((float)((bin*sub) & 4095)*C, &si, &cr);
  float cS, sS;  __sincosf((float)((bin*8)   & 4095)*C, &sS, &cS);
  float re = 0.f, im = 0.f;
  for (int k = 0; k < 512; k++){
    const float xv = row[(k<<3) + sub];
    re += xv*cr; im += xv*si;
    const float c2 = cr*cS - si*sS;
    si = cr*sS + si*cS;
    cr = c2;
  }
  re += __shfl_xor(re, 1, 8); im += __shfl_xor(im, 1, 8);
  re += __shfl_xor(re, 2, 8); im += __shfl_xor(im, 2, 8);
  re += __shfl_xor(re, 4, 8); im += __shfl_xor(im, 4, 8);
  if (sub == 0) mag[b*256 + chunk*32 + binl] = sqrtf(re*re + im*im);
}

__global__ void rowmax_kernel(const float* __restrict__ mag, float* __restrict__ rmax){
  const int b = blockIdx.x, t = threadIdx.x;
  __shared__ float r[256];
  r[t] = mag[b*256 + t]; __syncthreads();
  for (int o2 = 128; o2 > 0; o2 >>= 1){ if (t < o2) r[t] = fmaxf(r[t], r[t+o2]); __syncthreads(); }
  if (t == 0) rmax[b] = r[0];
}

__global__ void freq_kernel(const float* __restrict__ mag, const float* __restrict__ rmax,
                            const float* __restrict__ fw, const float* __restrict__ fb,
                            float* __restrict__ outp){
  const int b = blockIdx.x, j = threadIdx.x;  // 32
  const float mx = rmax[b];
  const float sc = mx > 0.f ? 1.0f/mx : 1.0f;
  float acc = fb[j];
  for (int i = 0; i < 256; i++) acc += (mag[b*256+i]*sc) * fw[(size_t)j*256 + i];
  outp[b*32 + j] = lrelu_f(acc);
}

__global__ void final_kernel(const float* __restrict__ xm, const float* __restrict__ l,
                             const float* __restrict__ fr, const float* __restrict__ fv,
                             const float* __restrict__ pv, const float* __restrict__ fcw,
                             const float* __restrict__ fcb, float* __restrict__ outp){
  const int b = blockIdx.x, j = threadIdx.x;  // 32 threads, 27 active
  if (j >= 27) return;
  float acc = fcb[j];
  const float* wr_ = fcw + (size_t)j*396;
  for (int i = 0; i < 256; i++) acc += xm[b*256+i] * wr_[i];
  for (int i = 0; i < 12;  i++) acc += l[b*12+i]   * wr_[256+i];
  for (int i = 0; i < 32;  i++) acc += fr[b*32+i]  * wr_[268+i];
  for (int i = 0; i < 64;  i++) acc += fv[b*64+i]  * wr_[300+i];
  for (int i = 0; i < 32;  i++) acc += pv[b*32+i]  * wr_[364+i];
  outp[b*27 + j] = acc;
  outp[64*27 + b*27 + j] = 1.0f/(1.0f + __expf(-acc));
}

// --------------------------- host side --------------------------------------
extern "C" void kernel_launch(void* const* d_in, const int* in_sizes, int n_in,
                              void* d_out, int out_size, void* d_ws, size_t ws_size,
                              hipStream_t stream)
{
  const float* x       = (const float*)d_in[0];
  const float* l       = (const float*)d_in[1];
  const float* conv_w  = (const float*)d_in[2];
  const float* bn0     = (const float*)d_in[3];
  const float* rb_c1   = (const float*)d_in[4];
  const float* rb_bn1  = (const float*)d_in[5];
  const float* rb_c2   = (const float*)d_in[6];
  const float* rb_bn2  = (const float*)d_in[7];
  const float* rb_id   = (const float*)d_in[8];
  const float* in_w    = (const float*)d_in[9];
  const float* in_b    = (const float*)d_in[10];
  const float* out_w   = (const float*)d_in[11];
  const float* out_b   = (const float*)d_in[12];
  const float* flut_w  = (const float*)d_in[13];
  const float* flut_b  = (const float*)d_in[14];
  const float* flut_bn = (const float*)d_in[15];
  const float* pvc_w   = (const float*)d_in[16];
  const float* pvc_b   = (const float*)d_in[17];
  const float* pvc_bn  = (const float*)d_in[18];
  const float* w_flut2 = (const float*)d_in[19];
  const float* w_pvc2  = (const float*)d_in[20];
  const float* freq_w  = (const float*)d_in[21];
  const float* freq_b  = (const float*)d_in[22];
  const float* fc_w    = (const float*)d_in[23];
  const float* fc_b    = (const float*)d_in[24];
  float* outp = (float*)d_out;

  char* ws = (char*)d_ws;
  size_t off = 0;
  auto alloc = [&](size_t bytes)->char*{ char* p = ws + off; off = (off + bytes + 255) & ~(size_t)255; return p; };

  // ---- persistent (~16.7 MiB) ----
  u16* wr    = (u16*)alloc((size_t)10*589824*2);   // 11.25 MiB res weights [slot][co][tap*256+ci]
  u16* wid   = (u16*)alloc((size_t)5*131072*2);    //  1.25 MiB identity 2-tap weights
  u16* w0p   = (u16*)alloc(131072);                //  conv0 weights, K-padded
  u16* wqkvb = (u16*)alloc(196608*2);              //  qkv proj weights bf16 (768,256)
  u16* woutb = (u16*)alloc(65536*2);               //  out proj weights bf16 (256,256)
  u16* h5b   = (u16*)alloc((size_t)64*64*256*2);   //  2 MiB (B*64,256) bf16
  u16* zbuf  = (u16*)alloc(256);                   //  16B+ zero page for OOB-tap clamp
  float* s0 = (float*)alloc(1024);  float* b0 = (float*)alloc(1024);
  float* s1 = (float*)alloc(5120);  float* b1 = (float*)alloc(5120);
  float* s2 = (float*)alloc(5120);  float* b2 = (float*)alloc(5120);
  float* xm    = (float*)alloc(65536);
  float* fpool = (float*)alloc((size_t)64*4096*4); // 1 MiB
  float* ppool = (float*)alloc((size_t)64*2048*4); // 0.5 MiB
  float* mag   = (float*)alloc(65536);
  float* rmax  = (float*)alloc(1024);
  float* fvecv = (float*)alloc(16384);
  float* pvecv = (float*)alloc(8192);
  float* freqv = (float*)alloc(8192);

  // ---- adaptive batch slice: chain arena = 2.625*sp MiB (bf16 activations) ----
  const size_t rem = (ws_size > off) ? (ws_size - off) : 0;
  int sp = 0;
  for (int c = 64; c >= 2; c >>= 1)
    if ((size_t)c*2752512 + (1<<20) <= rem){ sp = c; break; }
  if (sp == 0){ canary_kernel<<<14,256,0,stream>>>(outp); return; }

  u16* x16q = (u16*)alloc((size_t)sp*131072);      // (sp,4096,16) bf16
  u16* h0q  = (u16*)alloc((size_t)sp*1048576);     // (sp,2048,256) bf16
  u16* hCq  = (u16*)alloc((size_t)sp*524288);      // (sp,<=1024,256) bf16
  u16* ping = (u16*)alloc((size_t)sp*524288);
  u16* pong = (u16*)alloc((size_t)sp*524288);

  // ---- param prep (once) ----
  zerok_kernel<<<1,128,0,stream>>>(zbuf);
  bnfold_kernel<<<11,256,0,stream>>>(bn0, rb_bn1, rb_bn2, s0,b0,s1,b1,s2,b2);
  w0prep_kernel<<<256,256,0,stream>>>(conv_w, w0p);
  wrprep_kernel<<<dim3(256,10),256,0,stream>>>(rb_c1, rb_c2, wr);
  widprep_kernel<<<dim3(256,5),256,0,stream>>>(rb_id, wid);
  castb_kernel<<<768,256,0,stream>>>(in_w, wqkvb, 196608);
  castb_kernel<<<256,256,0,stream>>>(out_w, woutb, 65536);

  // ---- res chain: conv0 on gemm_conv; i=0 on gemm8; i=1 on gemm_conv;
  //      i>=2 on gemm_sm 64x128 tiles (r24: fills idle CUs at small layers) ----
  for (int s = 0; s < 64/sp; s++){
    const float* xs = x + (size_t)s*sp*49152;
    x16prep_kernel<<<dim3(16,sp),256,0,stream>>>(xs, x16q);
    // conv0: (sp,4096,16) -> (sp,2048,256), k=15 s=2 p=7, K padded to 256
    {
      const int mm = sp*16, nn = 2;
      gemm_conv<true,false,false><<<mm*nn,256,0,stream>>>(
          x16q - 112, w0p, nullptr, nullptr, h0q, s0, b0,
          256, 0, 11, 2, 4, 7, 4096, 65536, 32, 0, 0, 256, 256, 1, mm, nn);
    }
    int Lin = 2048;
    const u16* bin = h0q;
    for (int i = 0; i < 5; i++){
      const int Lo = Lin >> 1;
      const int lgLo = 10 - i;
      if (i < 1){
        // 8-phase 256x256 path (grid 256 blocks = 1 block/CU at sp=64)
        const int mb = sp*Lo/256;
        gemm8<false><<<mb,512,0,stream>>>(
            bin - 1024, wr + (size_t)i*589824, nullptr, nullptr, hCq, s1+i*256, b1+i*256, zbuf,
            2304, 0, lgLo, 2, 8, 4, Lin, Lin*256, 512, 0, 0);
        u16* bout = (i&1) ? pong : ping;
        gemm8<true><<<mb,512,0,stream>>>(
            hCq - 1024, wr + (size_t)(5+i)*589824, bin, wid + (size_t)i*131072,
            bout, s2+i*256, b2+i*256, zbuf,
            2304, 512, lgLo, 1, 8, 4, Lo, Lo*256, 256, Lin*256, 512);
        bin = bout;
      } else if (i == 1){
        // 128^2 kernel (512-block grid, 2/CU TLP)
        const int mm = sp*Lo/128, nn = 2;
        gemm_conv<true,false,false><<<mm*nn,256,0,stream>>>(
            bin - 1024, wr + (size_t)i*589824, nullptr, nullptr, hCq, s1+i*256, b1+i*256,
            2304, 0, lgLo, 2, 8, 4, Lin, Lin*256, 512, 0, 0, 256, 256, 1, mm, nn);
        u16* bout = (i&1) ? pong : ping;
        gemm_conv<true,true,false><<<mm*nn,256,0,stream>>>(
            hCq - 1024, wr + (size_t)(5+i)*589824, bin, wid + (size_t)i*131072,
            bout, s2+i*256, b2+i*256,
            2304, 512, lgLo, 1, 8, 4, Lo, Lo*256, 256, Lin*256, 512, 256, 256, 1, mm, nn);
        bin = bout;
      } else {
        // i>=2: 64x128 tiles double the grid (r24)
        const int mm = sp*Lo/64, nn = 2;
        gemm_sm<true,false,false><<<mm*nn,256,0,stream>>>(
            bin - 1024, wr + (size_t)i*589824, nullptr, nullptr, hCq, s1+i*256, b1+i*256,
            2304, 0, lgLo, 2, 8, 4, Lin, Lin*256, 512, 0, 0, 256, 256, 1, mm, nn);
        if (i < 4){
          u16* bout = (i&1) ? pong : ping;
          gemm_sm<true,true,false><<<mm*nn,256,0,stream>>>(
              hCq - 1024, wr + (size_t)(5+i)*589824, bin, wid + (size_t)i*131072,
              bout, s2+i*256, b2+i*256,
              2304, 512, lgLo, 1, 8, 4, Lo, Lo*256, 256, Lin*256, 512, 256, 256, 1, mm, nn);
          bin = bout;
        } else {
          gemm_sm<true,true,false><<<mm*nn,256,0,stream>>>(
              hCq - 1024, wr + (size_t)(5+i)*589824, bin, wid + (size_t)i*131072,
              h5b + (size_t)s*sp*16384, s2+i*256, b2+i*256,
              2304, 512, lgLo, 1, 8, 4, Lo, Lo*256, 256, Lin*256, 512, 256, 256, 1, mm, nn);
        }
      }
      Lin = Lo;
    }
  }

  // ---- MHA on MFMA GEMMs; slice if arena is small ----
  {
    const int nsl = (sp >= 8) ? 1 : 4;
    const int rows = 4096/nsl;                       // 64*samples per slice
    float* qkvF = (float*)x16q;                      // arena aliases (chain is dead)
    u16*   o_b  = (u16*)(qkvF + (size_t)rows*768);
    float* omF  = (float*)(o_b + (size_t)rows*256);
    for (int s = 0; s < nsl; s++){
      const int mm = rows/128;
      gemm_conv<false,false,true><<<mm*6,256,0,stream>>>(
          h5b + (size_t)s*rows*256, wqkvb, nullptr, nullptr, qkvF, nullptr, in_b,
          256, 0, 12, 1, 8, 0, 0, 0, 256, 0, 0, 768, 768, 0, mm, 6);
      attn3<<<(rows/64)*8,64,0,stream>>>(qkvF, o_b);
      gemm_conv<false,false,true><<<mm*2,256,0,stream>>>(
          o_b, woutb, nullptr, nullptr, omF, nullptr, out_b,
          256, 0, 12, 1, 8, 0, 0, 0, 256, 0, 0, 256, 256, 0, mm, 2);
      xmain_s<<<rows/64,256,0,stream>>>(omF, xm, s*(rows/64));
    }
  }

  // ---- lead_II branch: single fused kernel (conv+bn+lrelu+pool x2) ----
  leadii_fused<<<dim3(4,64),256,0,stream>>>(x, flut_w, flut_b, flut_bn,
                                            pvc_w, pvc_b, pvc_bn, fpool, ppool);
  fcdot_kernel<64,4096><<<dim3(64,64),256,0,stream>>>(fpool, w_flut2, fvecv);
  fcdot_kernel<32,2048><<<dim3(64,32),256,0,stream>>>(ppool, w_pvc2, pvecv);

  // ---- FFT branch (LDS-staged DFT) ----
  fft2_kernel<<<dim3(64,8),256,0,stream>>>(x, mag);
  rowmax_kernel<<<64,256,0,stream>>>(mag, rmax);
  freq_kernel<<<64,32,0,stream>>>(mag, rmax, freq_w, freq_b, freqv);

  // ---- combine + logits + sigmoid ----
  final_kernel<<<64,32,0,stream>>>(xm, l, freqv, fvecv, pvecv, fc_w, fc_b, outp);
  (void)in_sizes; (void)n_in; (void)out_size;
}

// Round 12
// 985.614 us; speedup vs baseline: 1.0792x; 1.0792x over previous
//
#include <hip/hip_runtime.h>

typedef unsigned short u16;
typedef unsigned int   u32;
typedef __attribute__((ext_vector_type(8))) short short8;   // 8 x bf16 (4 VGPRs)
typedef __attribute__((ext_vector_type(4))) float f32x4;    // MFMA accumulator

__device__ __forceinline__ float bf2f(u16 u){ return __uint_as_float(((u32)u)<<16); }
__device__ __forceinline__ u16 f2bf(float f){ u32 x = __float_as_uint(f); x += 0x7fffu + ((x>>16)&1u); return (u16)(x>>16); }
__device__ __forceinline__ float lrelu_f(float v){ return v >= 0.0f ? v : 0.01f*v; }

#if defined(__has_builtin)
#if __has_builtin(__builtin_amdgcn_global_load_lds)
#define HAS_GLL 1
#endif
#endif
#ifndef HAS_GLL
#define HAS_GLL 0
#endif

// async global->LDS DMA, 16B per lane; LDS dst = l + lane*16 (wave-uniform l).
// Defined unconditionally: host pass lacks the builtin (__has_builtin false on
// host target), so it gets a parse-only stub; device pass on gfx950 uses DMA.
__device__ __forceinline__ void gll16(const u16* g, u16* l){
#if HAS_GLL
  __builtin_amdgcn_global_load_lds(
      (__attribute__((address_space(1))) void*)(void*)g,
      (__attribute__((address_space(3))) void*)l, 16, 0, 0);
#else
  *(uint4*)l = *(const uint4*)g;   // never executed on gfx950; host-parse stub
#endif
}

// compiler-level memory fence around the HW barrier: prevents LDS/VMEM ops
// migrating across; MFMA/VALU may still move (harmless).
#define SBAR() { asm volatile("" ::: "memory"); __builtin_amdgcn_s_barrier(); asm volatile("" ::: "memory"); }
#define VMW(N) asm volatile("s_waitcnt vmcnt(" #N ")" ::: "memory")

// ---------------------------------------------------------------------------
// Implicit-GEMM conv (PROVEN r10/r12 config — conv0, i=1, MHA):
// Tile 128x128, BK=64, 4 waves x (4x4 of 16x16x32 bf16 MFMA), single acc,
// XOR-swizzled LDS, global_load_lds fast path, XCD-aware 1D grid decode.
// ---------------------------------------------------------------------------
template<bool PRED1, bool DUAL, bool F32OUT>
__global__ __launch_bounds__(256, 4) void gemm_conv(
    const u16* __restrict__ A1, const u16* __restrict__ B1,
    const u16* __restrict__ A2, const u16* __restrict__ B2,
    void* __restrict__ Out, const float* __restrict__ scale,
    const float* __restrict__ bias,
    int K1, int K2, int lgLo, int S1, int lgCin1, int P1, int Lin1,
    int Abatch1, int Arow1, int Abatch2, int Arow2,
    int Ncols, int Cout, int lrelu, int Mblks, int Nblks)
{
  __shared__ u16 ldsA[128*64];
  __shared__ u16 ldsB[128*64];
  const int tid = threadIdx.x;
  int nblk, mblk;
  {
    const int bid = blockIdx.x;
    if (Mblks & 7){ nblk = bid % Nblks; mblk = bid / Nblks; }
    else { const int grp = Nblks*8; const int g = bid/grp; const int r = bid - g*grp;
           nblk = r >> 3; mblk = g*8 + (r & 7); }
  }
  const int wv = tid >> 6, lane = tid & 63;
  const int mbase = (wv & 1)*64, nbase = (wv >> 1)*64;
  const int lq = lane >> 4, lm = lane & 15;
  const int sw = lm & 7;                            // fragment-read swizzle key

  f32x4 acc[4][4];
#pragma unroll
  for (int a_=0;a_<4;a_++)
#pragma unroll
    for (int b_=0;b_<4;b_++) acc[a_][b_] = (f32x4){0.f,0.f,0.f,0.f};

  float scv[4], biv[4];
  if constexpr (DUAL){
#pragma unroll
    for (int nt=0;nt<4;nt++){
      const int colg = nblk*128 + nbase + nt*16 + lm;   // DUAL: Ncols==Cout==256, in-range
      scv[nt] = scale[colg]; biv[nt] = bias[colg];
    }
  }

  auto mfma_step = [&](){
#pragma unroll
    for (int kk=0; kk<2; kk++){
      const int s8 = (((kk*4+lq) ^ sw) << 3);
      short8 af[4], bfr[4];
#pragma unroll
      for (int mt=0;mt<4;mt++) af[mt]  = *(const short8*)&ldsA[(mbase+mt*16+lm)*64 + s8];
#pragma unroll
      for (int nt=0;nt<4;nt++) bfr[nt] = *(const short8*)&ldsB[(nbase+nt*16+lm)*64 + s8];
#pragma unroll
      for (int mt=0;mt<4;mt++)
#pragma unroll
        for (int nt=0;nt<4;nt++)
          acc[mt][nt] = __builtin_amdgcn_mfma_f32_16x16x32_bf16(af[mt], bfr[nt], acc[mt][nt], 0,0,0);
    }
  };
  auto xform = [&](){                     // in-place epilogue at phase boundary
#pragma unroll
    for (int mt=0;mt<4;mt++)
#pragma unroll
      for (int nt=0;nt<4;nt++)
#pragma unroll
        for (int r=0;r<4;r++){
          float v = acc[mt][nt][r]*scv[nt] + biv[nt];
          acc[mt][nt][r] = lrelu ? lrelu_f(v) : v;
        }
  };

  const int Ktot = DUAL ? (K1 + K2) : K1;

  // wave-uniform interior test: unpredicated A reads for the whole m-tile?
  bool fast = (HAS_GLL != 0);
  if (PRED1 && fast){
    const int Lo = 1 << lgLo;
    if (Lo < 128) fast = false;
    else {
      const int lo0 = (mblk*128) & (Lo-1);
      const int taps = K1 >> lgCin1;
      fast = (lo0*S1 - P1 >= 0) && ((lo0+127)*S1 + taps - 1 - P1 < Lin1);
    }
  }

#if HAS_GLL
  if (fast){
    // Fast path: Lo>=128, tiles 128-aligned -> z constant per tile.
    const int pm0 = mblk*128;
    const int z0  = pm0 >> lgLo;
    const int lo0 = pm0 & ((1<<lgLo)-1);
    const int lr  = lane >> 3;
    const int lc8 = (lane & 7) ^ lr;              // swizzled chunk for this lane
    const u16* pA = A1 + (long)z0*Abatch1 + (long)(lo0 + wv*32 + lr)*Arow1 + lc8*8;
    const u16* pB = B1 + (long)(nblk*128 + wv*32 + lr)*K1 + lc8*8;
    long strA = Arow1, strB = K1;
    u16* da = &ldsA[(wv*32)*64];
    u16* db = &ldsB[(wv*32)*64];
    for (int k0 = 0; k0 < Ktot; k0 += 64){
      int kk = k0;
      if constexpr (DUAL){
        if (k0 >= K1){
          if (k0 == K1){
            pA = A2 + (long)z0*Abatch2 + (long)(lo0 + wv*32 + lr)*Arow2 + lc8*8;
            pB = B2 + (long)(nblk*128 + wv*32 + lr)*K2 + lc8*8;
            strA = Arow2; strB = K2;
          }
          kk = k0 - K1;
        }
      }
      __syncthreads();
#pragma unroll
      for (int u=0; u<4; u++) gll16(pA + (long)u*8*strA + kk, da + u*8*64);
#pragma unroll
      for (int u=0; u<4; u++) gll16(pB + (long)u*8*strB + kk, db + u*8*64);
      __syncthreads();      // drains DMA -> writes visible
      if constexpr (DUAL){ if (k0 == K1) xform(); }
      mfma_step();
    }
  } else
#endif
  {
    // predicated VGPR staging (zero-fills OOB taps), swizzled layout
    const int sr  = tid >> 1;
    const int cg  = (tid & 1)*4;
    const int pmS = mblk*128 + sr;
    const int zS  = pmS >> lgLo;
    const int loS = pmS & ((1<<lgLo)-1);
    const long aoff1 = (long)zS*Abatch1 + (long)loS*Arow1;
    long aoff2 = 0;
    if constexpr (DUAL) aoff2 = (long)zS*Abatch2 + (long)loS*Arow2;
    const int coS = nblk*128 + sr;
    const long boff1 = (long)coS*K1;
    long boff2 = 0;
    if constexpr (DUAL) boff2 = (long)coS*K2;
    const int ssw = sr & 7;

    for (int k0 = 0; k0 < Ktot; k0 += 64){
      const bool ph1 = !DUAL || (k0 < K1);
      __syncthreads();
      {
        const u16* asrc = ph1 ? (A1 + aoff1 + k0) : (A2 + aoff2 + (k0 - K1));
#pragma unroll
        for (int u=0; u<4; u++){
          const int c = cg + u;
          uint4 v; v.x=0u; v.y=0u; v.z=0u; v.w=0u;
          bool ok = true;
          if (PRED1 && ph1){
            int tap = (k0 + c*8) >> lgCin1;
            int pos = loS*S1 + tap - P1;
            ok = ((u32)pos < (u32)Lin1);
          }
          if (ok) v = *(const uint4*)(asrc + c*8);
          *(uint4*)&ldsA[sr*64 + ((c ^ ssw)*8)] = v;
        }
      }
      {
        const u16* bsrc = ph1 ? (B1 + boff1 + k0) : (B2 + boff2 + (k0 - K1));
#pragma unroll
        for (int u=0; u<4; u++){
          const int c = cg + u;
          uint4 v = *(const uint4*)(bsrc + c*8);
          *(uint4*)&ldsB[sr*64 + ((c ^ ssw)*8)] = v;
        }
      }
      __syncthreads();
      if constexpr (DUAL){ if (k0 == K1) xform(); }
      mfma_step();
    }
  }

  // epilogue: DUAL acc is already final (transform applied at boundary + id)
#pragma unroll
  for (int nt=0;nt<4;nt++){
    const int colg = nblk*128 + nbase + nt*16 + lm;
    if (colg >= Ncols) continue;
    float sc = 1.0f, bi = 0.0f;
    if constexpr (!DUAL){
      if (scale) sc = scale[colg];
      if (bias)  bi = bias[colg];
    }
#pragma unroll
    for (int mt=0;mt<4;mt++){
#pragma unroll
      for (int r=0;r<4;r++){
        const long pm = (long)mblk*128 + mbase + mt*16 + lq*4 + r;
        float v = acc[mt][nt][r];
        if constexpr (!DUAL){
          v = v*sc + bi;
          if (lrelu) v = lrelu_f(v);
        }
        if constexpr (F32OUT) ((float*)Out)[pm*Cout + colg] = v;
        else                  ((u16*)Out)[pm*Cout + colg] = f2bf(v);
      }
    }
  }
}

// ---------------------------------------------------------------------------
// r24: 64x128-tile sibling (gemm_sm) for deep layers i>=2, where the 128^2
// grids leave CUs idle (i=3: half, i=4: three-quarters). Same 2-barrier loop,
// same XOR-swizzle (row&7 == lm&7 on reads), same gll fast path / predicated
// fallback. 4 waves each own 64 rows x 32 cols (acc[4][2]); LDS 24 KiB.
// Grids double: i=2 512 blk (2/CU), i=3 256 (full), i=4 128. Extra B re-reads
// are L2-resident weights (~1.2 MB/layer).
// ---------------------------------------------------------------------------
template<bool PRED1, bool DUAL, bool F32OUT>
__global__ __launch_bounds__(256, 4) void gemm_sm(
    const u16* __restrict__ A1, const u16* __restrict__ B1,
    const u16* __restrict__ A2, const u16* __restrict__ B2,
    void* __restrict__ Out, const float* __restrict__ scale,
    const float* __restrict__ bias,
    int K1, int K2, int lgLo, int S1, int lgCin1, int P1, int Lin1,
    int Abatch1, int Arow1, int Abatch2, int Arow2,
    int Ncols, int Cout, int lrelu, int Mblks, int Nblks)
{
  __shared__ u16 ldsA[64*64];
  __shared__ u16 ldsB[128*64];
  const int tid = threadIdx.x;
  int nblk, mblk;
  {
    const int bid = blockIdx.x;
    if (Mblks & 7){ nblk = bid % Nblks; mblk = bid / Nblks; }
    else { const int grp = Nblks*8; const int g = bid/grp; const int r = bid - g*grp;
           nblk = r >> 3; mblk = g*8 + (r & 7); }
  }
  const int wv = tid >> 6, lane = tid & 63;
  const int lq = lane >> 4, lm = lane & 15;
  const int sw = lm & 7;

  f32x4 acc[4][2];
#pragma unroll
  for (int a_=0;a_<4;a_++)
#pragma unroll
    for (int b_=0;b_<2;b_++) acc[a_][b_] = (f32x4){0.f,0.f,0.f,0.f};

  float scv[2], biv[2];
  if constexpr (DUAL){
#pragma unroll
    for (int nt=0;nt<2;nt++){
      const int colg = nblk*128 + wv*32 + nt*16 + lm;
      scv[nt] = scale[colg]; biv[nt] = bias[colg];
    }
  }

  auto mfma_step = [&](){
#pragma unroll
    for (int kk=0; kk<2; kk++){
      const int s8 = (((kk*4+lq) ^ sw) << 3);
      short8 af[4], bfr[2];
#pragma unroll
      for (int mt=0;mt<4;mt++) af[mt]  = *(const short8*)&ldsA[(mt*16+lm)*64 + s8];
#pragma unroll
      for (int nt=0;nt<2;nt++) bfr[nt] = *(const short8*)&ldsB[(wv*32+nt*16+lm)*64 + s8];
#pragma unroll
      for (int mt=0;mt<4;mt++)
#pragma unroll
        for (int nt=0;nt<2;nt++)
          acc[mt][nt] = __builtin_amdgcn_mfma_f32_16x16x32_bf16(af[mt], bfr[nt], acc[mt][nt], 0,0,0);
    }
  };
  auto xform = [&](){
#pragma unroll
    for (int mt=0;mt<4;mt++)
#pragma unroll
      for (int nt=0;nt<2;nt++)
#pragma unroll
        for (int r=0;r<4;r++){
          float v = acc[mt][nt][r]*scv[nt] + biv[nt];
          acc[mt][nt][r] = lrelu ? lrelu_f(v) : v;
        }
  };

  const int Ktot = DUAL ? (K1 + K2) : K1;

  // wave-uniform interior test for the 64-row m-tile
  bool fast = (HAS_GLL != 0);
  if (PRED1 && fast){
    const int Lo = 1 << lgLo;
    if (Lo < 64) fast = false;
    else {
      const int lo0 = (mblk*64) & (Lo-1);
      const int taps = K1 >> lgCin1;
      fast = (lo0*S1 - P1 >= 0) && ((lo0+63)*S1 + taps - 1 - P1 < Lin1);
    }
  }

#if HAS_GLL
  if (fast){
    const int pm0 = mblk*64;
    const int z0  = pm0 >> lgLo;
    const int lo0 = pm0 & ((1<<lgLo)-1);
    const int lr  = lane >> 3;
    const int lc8 = (lane & 7) ^ lr;              // swizzled chunk (row&7 == lr)
    const u16* pA = A1 + (long)z0*Abatch1 + (long)(lo0 + wv*16 + lr)*Arow1 + lc8*8;
    const u16* pB = B1 + (long)(nblk*128 + wv*32 + lr)*K1 + lc8*8;
    long strA = Arow1, strB = K1;
    u16* da = &ldsA[(wv*16)*64];
    u16* db = &ldsB[(wv*32)*64];
    for (int k0 = 0; k0 < Ktot; k0 += 64){
      int kk = k0;
      if constexpr (DUAL){
        if (k0 >= K1){
          if (k0 == K1){
            pA = A2 + (long)z0*Abatch2 + (long)(lo0 + wv*16 + lr)*Arow2 + lc8*8;
            pB = B2 + (long)(nblk*128 + wv*32 + lr)*K2 + lc8*8;
            strA = Arow2; strB = K2;
          }
          kk = k0 - K1;
        }
      }
      __syncthreads();
#pragma unroll
      for (int u=0; u<2; u++) gll16(pA + (long)u*8*strA + kk, da + u*8*64);
#pragma unroll
      for (int u=0; u<4; u++) gll16(pB + (long)u*8*strB + kk, db + u*8*64);
      __syncthreads();
      if constexpr (DUAL){ if (k0 == K1) xform(); }
      mfma_step();
    }
  } else
#endif
  {
    // predicated VGPR staging: A 64 rows (4 thr/row x 2 chunks), B 128 rows
    const int srA = tid >> 2;                    // 0..63
    const int cgA = (tid & 3)*2;                 // 0,2,4,6
    const int pmS = mblk*64 + srA;
    const int zS  = pmS >> lgLo;
    const int loS = pmS & ((1<<lgLo)-1);
    const long aoff1 = (long)zS*Abatch1 + (long)loS*Arow1;
    long aoff2 = 0;
    if constexpr (DUAL) aoff2 = (long)zS*Abatch2 + (long)loS*Arow2;
    const int sswA = srA & 7;
    const int srB = tid >> 1;                    // 0..127
    const int cgB = (tid & 1)*4;
    const int coS = nblk*128 + srB;
    const long boff1 = (long)coS*K1;
    long boff2 = 0;
    if constexpr (DUAL) boff2 = (long)coS*K2;
    const int sswB = srB & 7;

    for (int k0 = 0; k0 < Ktot; k0 += 64){
      const bool ph1 = !DUAL || (k0 < K1);
      __syncthreads();
      {
        const u16* asrc = ph1 ? (A1 + aoff1 + k0) : (A2 + aoff2 + (k0 - K1));
#pragma unroll
        for (int u=0; u<2; u++){
          const int c = cgA + u;
          uint4 v; v.x=0u; v.y=0u; v.z=0u; v.w=0u;
          bool ok = true;
          if (PRED1 && ph1){
            int tap = (k0 + c*8) >> lgCin1;
            int pos = loS*S1 + tap - P1;
            ok = ((u32)pos < (u32)Lin1);
          }
          if (ok) v = *(const uint4*)(asrc + c*8);
          *(uint4*)&ldsA[srA*64 + ((c ^ sswA)*8)] = v;
        }
      }
      {
        const u16* bsrc = ph1 ? (B1 + boff1 + k0) : (B2 + boff2 + (k0 - K1));
#pragma unroll
        for (int u=0; u<4; u++){
          const int c = cgB + u;
          uint4 v = *(const uint4*)(bsrc + c*8);
          *(uint4*)&ldsB[srB*64 + ((c ^ sswB)*8)] = v;
        }
      }
      __syncthreads();
      if constexpr (DUAL){ if (k0 == K1) xform(); }
      mfma_step();
    }
  }

#pragma unroll
  for (int nt=0;nt<2;nt++){
    const int colg = nblk*128 + wv*32 + nt*16 + lm;
    if (colg >= Ncols) continue;
    float sc = 1.0f, bi = 0.0f;
    if constexpr (!DUAL){
      if (scale) sc = scale[colg];
      if (bias)  bi = bias[colg];
    }
#pragma unroll
    for (int mt=0;mt<4;mt++){
#pragma unroll
      for (int r=0;r<4;r++){
        const long pm = (long)mblk*64 + mt*16 + lq*4 + r;
        float v = acc[mt][nt][r];
        if constexpr (!DUAL){
          v = v*sc + bi;
          if (lrelu) v = lrelu_f(v);
        }
        if constexpr (F32OUT) ((float*)Out)[pm*Cout + colg] = v;
        else                  ((u16*)Out)[pm*Cout + colg] = f2bf(v);
      }
    }
  }
}

// ---------------------------------------------------------------------------
// r21/r22/r23: 256x256 engine, two-barrier deep-prefetch KTILE (measured-best).
// Engine placement (measured): gemm8 ONLY for i=0; gemm_conv for conv0, i=1,
// MHA; gemm_sm (r24) for i>=2. gemm8 structure iteration CLOSED.
// ---------------------------------------------------------------------------
#define RDA(BUF, MH) {                                                     \
  _Pragma("unroll") for (int mt=0; mt<4; mt++)                             \
  _Pragma("unroll") for (int kk=0; kk<2; kk++)                             \
    Ar[mt][kk] = *(const short8*)&ldsA[BUF][(((wr<<7) + (((MH)*4+mt)<<4) + lm)<<6) + (((kk*4+lq)^sw)<<3)]; }
#define RDB(BUF, NH, RB) {                                                 \
  _Pragma("unroll") for (int nt=0; nt<2; nt++)                             \
  _Pragma("unroll") for (int kk=0; kk<2; kk++)                             \
    RB[nt][kk] = *(const short8*)&ldsB[BUF][(((wc<<6) + (((NH)*2+nt)<<4) + lm)<<6) + (((kk*4+lq)^sw)<<3)]; }
#define MME(MH, NH, RB) {                                                  \
  __builtin_amdgcn_s_setprio(1);                                           \
  _Pragma("unroll") for (int mt=0; mt<4; mt++)                             \
  _Pragma("unroll") for (int nt=0; nt<2; nt++)                             \
  _Pragma("unroll") for (int kk=0; kk<2; kk++)                             \
    acc[(MH)*4+mt][(NH)*2+nt] = __builtin_amdgcn_mfma_f32_16x16x32_bf16(   \
        Ar[mt][kk], RB[nt][kk], acc[(MH)*4+mt][(NH)*2+nt], 0,0,0);         \
  __builtin_amdgcn_s_setprio(0); }

// One K-tile = 4 phases. Stages target tile G+2 (same BUF), each slot staged
// immediately after its last ds_read retired (enforced by the barrier pair of
// the phase where it was read). vmcnt(8) at P4 = tile G+1 fully landed (its 8
// loads were issued in iteration G-1, >=4 phases ago); in-flight = tile G+2.
#define KTILE(G, BUF) {                                                    \
  if constexpr (DUAL){ if ((G) == t1) xf(); }                              \
  /* P1: A-ev + B-ev of tile G */                                          \
  RDA(BUF, 0); RDB(BUF, 0, Br0);                                           \
  SBAR(); MME(0,0,Br0); SBAR();                                            \
  /* P2: B-od of tile G; stage A-ev(G+2) (slot freed by P1 barrier) */     \
  RDB(BUF, 1, Br1);                                                        \
  if ((G)+2 < nT) stA((G)+2, 0);                                           \
  SBAR(); MME(0,1,Br1); SBAR();                                            \
  /* P3: A-od of tile G; stage B-ev+B-od(G+2) (freed P1/P2) */             \
  RDA(BUF, 1);                                                             \
  if ((G)+2 < nT){ stB((G)+2, 0); stB((G)+2, 1); }                         \
  SBAR(); MME(1,0,Br0); SBAR();                                            \
  /* P4: stage A-od(G+2) (freed P3); counted wait for tile G+1 */          \
  if ((G)+2 < nT) stA((G)+2, 1);                                           \
  SBAR(); MME(1,1,Br1);                                                    \
  if ((G)+2 < nT) { VMW(8); } else { VMW(0); }                             \
  SBAR(); }

template<bool DUAL>
__global__ __launch_bounds__(512, 2) void gemm8(
    const u16* __restrict__ A1, const u16* __restrict__ B1,
    const u16* __restrict__ A2, const u16* __restrict__ B2,
    u16* __restrict__ Out, const float* __restrict__ scale,
    const float* __restrict__ bias, const u16* __restrict__ zb,
    int K1, int K2, int lgLo, int S1, int lgCin1, int P1, int Lin1,
    int Abatch1, int Arow1, int Abatch2, int Arow2)
{
  __shared__ u16 ldsA[2][16384];     // [buf][256 rows][64]
  __shared__ u16 ldsB[2][16384];

  const int tid  = threadIdx.x;
  const int wv   = tid >> 6, lane = tid & 63;
  const int wr   = wv >> 2, wc = wv & 3;
  const int lq   = lane >> 4, lm = lane & 15, sw = lm & 7;
  const int lr   = lane >> 3;
  const int cG   = (lane & 7) ^ lr;                 // pre-swizzled global chunk

  const int pm0 = blockIdx.x << 8;
  const int z0  = pm0 >> lgLo;
  const int lo0 = pm0 & ((1 << lgLo) - 1);

  const u16* baA1 = A1 + (long)z0*Abatch1 + (long)(lo0 + lr)*Arow1 + cG*8;
  const u16* baB1 = B1 + (long)lr*K1 + cG*8;
  const u16* baA2 = nullptr; const u16* baB2 = nullptr;
  if constexpr (DUAL){
    baA2 = A2 + (long)z0*Abatch2 + (long)(lo0 + lr)*Arow2 + cG*8;
    baB2 = B2 + (long)lr*K2 + cG*8;
  }
  const int posL = (lo0 + lr)*S1 - P1;              // per-lane pos base
  const int nT = (DUAL ? (K1 + K2) : K1) >> 6;
  const int t1 = DUAL ? (K1 >> 6) : 0x7fffffff;

  // block-uniform: no A tap can fall outside [0, Lin1) for this m-tile?
  bool interior;
  {
    const int taps = K1 >> lgCin1;
    interior = (lo0*S1 - P1 >= 0) && ((lo0+255)*S1 + taps - 1 - P1 < Lin1);
  }

  f32x4 acc[8][4];
#pragma unroll
  for (int a_=0;a_<8;a_++)
#pragma unroll
    for (int b_=0;b_<4;b_++) acc[a_][b_] = (f32x4){0.f,0.f,0.f,0.f};

  float scv[4], biv[4];
  if constexpr (DUAL){
#pragma unroll
    for (int nt=0;nt<4;nt++){
      const int colg = (wc<<6) + (nt<<4) + lm;
      scv[nt] = scale[colg]; biv[nt] = bias[colg];
    }
  }
  auto xf = [&](){                 // DUAL boundary transform (bn+lrelu on conv part)
#pragma unroll
    for (int mt=0;mt<8;mt++)
#pragma unroll
      for (int nt=0;nt<4;nt++)
#pragma unroll
        for (int r=0;r<4;r++){
          float v = acc[mt][nt][r]*scv[nt] + biv[nt];
          acc[mt][nt][r] = lrelu_f(v);
        }
  };

  // stage one A quarter-pair unit (16KiB, 2 gll/thread) of K-tile tau
  auto stA = [&](int tau, int odd){
    u16* dbase = &ldsA[tau & 1][0];
#pragma unroll
    for (int u=0; u<2; u++){
      const int riu = (wv<<4) + (u<<3);                       // 0..120, wave-uniform
      const int rl  = riu + (odd<<6) + ((riu >= 64) ? 64 : 0);// LDS/global row base
      u16* dst = dbase + (rl<<6);
      if (tau < t1){
        const int kloc = tau << 6;
        const u16* src = baA1 + (long)rl*Arow1 + kloc;
        if (!interior){
          const int tap = (kloc + cG*8) >> lgCin1;
          const int pos = posL + rl*S1 + tap;
          if ((u32)pos >= (u32)Lin1) src = zb;                // per-lane zero-page clamp
        }
        gll16(src, dst);
      } else {
        const int kloc = (tau << 6) - K1;                     // identity path: never OOB
        gll16(baA2 + (long)rl*Arow2 + kloc, dst);
      }
    }
  };
  // stage one B quarter-pair unit
  auto stB = [&](int tau, int odd){
    u16* dbase = &ldsB[tau & 1][0];
#pragma unroll
    for (int u=0; u<2; u++){
      const int riu = (wv<<4) + (u<<3);
      const int cl  = (riu & 31) + ((riu >> 5) << 6) + (odd << 5);
      u16* dst = dbase + (cl<<6);
      if (tau < t1) gll16(baB1 + (long)cl*K1 + (tau<<6), dst);
      else          gll16(baB2 + (long)cl*K2 + ((tau<<6) - K1), dst);
    }
  };

  short8 Ar[4][2], Br0[2][2], Br1[2][2];

  // prologue: tiles 0 and 1 fully staged -> vmcnt(8) = tile0 landed (tile1 in flight)
  stA(0,0); stA(0,1); stB(0,0); stB(0,1);
  if (nT > 1){ stA(1,0); stA(1,1); stB(1,0); stB(1,1); }
  VMW(8); SBAR();

  for (int g2 = 0; g2 < nT; g2 += 2){     // nT even
    KTILE(g2,   0);
    KTILE(g2+1, 1);
  }
  asm volatile("s_waitcnt vmcnt(0)" ::: "memory");

  // epilogue (Cout==256): non-DUAL applies bn+lrelu; DUAL acc already final
#pragma unroll
  for (int nt=0; nt<4; nt++){
    const int colg = (wc<<6) + (nt<<4) + lm;
    float sc = 1.0f, bi = 0.0f;
    if constexpr (!DUAL){ sc = scale[colg]; bi = bias[colg]; }
#pragma unroll
    for (int mt=0; mt<8; mt++){
#pragma unroll
      for (int r=0; r<4; r++){
        const long pm = (long)pm0 + (wr<<7) + (mt<<4) + (lq<<2) + r;
        float v = acc[mt][nt][r];
        if constexpr (!DUAL) v = lrelu_f(v*sc + bi);
        Out[pm*256 + colg] = f2bf(v);
      }
    }
  }
}

#undef RDA
#undef RDB
#undef MME
#undef KTILE

// --------------------------- prep kernels (fp32 -> bf16) --------------------
__global__ void bnfold_kernel(
    const float* __restrict__ bn0, const float* __restrict__ rbn1, const float* __restrict__ rbn2,
    float* s0, float* b0, float* s1, float* b1, float* s2, float* b2)
{
  const int blk = blockIdx.x, t = threadIdx.x;   // t < 256
  const float* p; float *so, *bo;
  if (blk == 0){ p = bn0; so = s0; bo = b0; }
  else if (blk <= 5){ int i = blk-1; p = rbn1 + i*1024; so = s1+i*256; bo = b1+i*256; }
  else { int i = blk-6; p = rbn2 + i*1024; so = s2+i*256; bo = b2+i*256; }
  const float g = p[t], be = p[256+t], m = p[512+t], v = p[768+t];
  const float sc = g / sqrtf(v + 1e-5f);
  so[t] = sc; bo[t] = be - m*sc;
}

__global__ void w0prep_kernel(const float* __restrict__ cw, u16* __restrict__ w0p){
  const int co = blockIdx.x, k = threadIdx.x;
  const int tp = k >> 4, ci = k & 15;
  u16 v = 0;
  if (tp < 15 && ci < 12) v = f2bf(cw[(co*12 + ci)*15 + tp]);
  w0p[co*256 + k] = v;
}

// coalesced: threads walk the 2304-elem source row contiguously
__global__ void wrprep_kernel(const float* __restrict__ c1, const float* __restrict__ c2, u16* __restrict__ wr){
  const int co = blockIdx.x, slot = blockIdx.y;
  const float* src = (slot < 5) ? (c1 + (size_t)slot*589824 + (size_t)co*2304)
                                : (c2 + (size_t)(slot-5)*589824 + (size_t)co*2304);
  u16* dst = wr + (size_t)slot*589824 + (size_t)co*2304;
  for (int k = threadIdx.x; k < 2304; k += 256){
    const int ci = k/9, tp = k - ci*9;
    dst[tp*256 + ci] = f2bf(src[k]);
  }
}

__global__ void widprep_kernel(const float* __restrict__ idw, u16* __restrict__ wid){
  const int co = blockIdx.x, sl = blockIdx.y, ci = threadIdx.x;
  u16 h = f2bf(0.5f * idw[((size_t)sl*256 + co)*256 + ci]);
  u16* dst = wid + (size_t)sl*131072 + co*512;
  dst[ci] = h; dst[256 + ci] = h;
}

__global__ void x16prep_kernel(const float* __restrict__ x, u16* __restrict__ x16){
  const int p = blockIdx.x*256 + threadIdx.x;
  const int b = blockIdx.y;
  u16 v[16];
#pragma unroll
  for (int ci=0; ci<16; ci++) v[ci] = (ci < 12) ? f2bf(x[((size_t)(b*12+ci))*4096 + p]) : (u16)0;
  uint4 A4, B4;
  A4.x = v[0] | ((u32)v[1]<<16); A4.y = v[2] | ((u32)v[3]<<16);
  A4.z = v[4] | ((u32)v[5]<<16); A4.w = v[6] | ((u32)v[7]<<16);
  B4.x = v[8] | ((u32)v[9]<<16); B4.y = v[10]| ((u32)v[11]<<16);
  B4.z = v[12]| ((u32)v[13]<<16); B4.w = v[14]| ((u32)v[15]<<16);
  uint4* dst = (uint4*)&x16[((size_t)b*4096 + p)*16];
  dst[0] = A4; dst[1] = B4;
}

// generic fp32 -> bf16 cast
__global__ void castb_kernel(const float* __restrict__ src, u16* __restrict__ dst, int n){
  const int i = blockIdx.x*256 + threadIdx.x;
  if (i < n) dst[i] = f2bf(src[i]);
}

__global__ void zerok_kernel(u16* __restrict__ zb){ zb[threadIdx.x] = 0; }

__global__ void canary_kernel(float* __restrict__ outp){
  const int idx = blockIdx.x*256 + threadIdx.x;
  if (idx < 3456) outp[idx] = 131072.0f;
}

// --------------------------- fp32 kernels -----------------------------------
// r18: fused lead-II branch. One kernel does BOTH convs (flut k=15 s=2 p=7,
// pvc k=9 s=2 p=4) + bn + lrelu + both max-pools, never materializing the
// (64,64,2048) activations (saves ~134 MB of fp32 traffic + 3 launches).
__global__ __launch_bounds__(256) void leadii_fused(
    const float* __restrict__ x,
    const float* __restrict__ fwg, const float* __restrict__ fbc, const float* __restrict__ fbn,
    const float* __restrict__ pwg, const float* __restrict__ pbc, const float* __restrict__ pbn,
    float* __restrict__ fp, float* __restrict__ pp)
{
  __shared__ float ldin[1040];
  const int opart = blockIdx.x;            // output chunk [opart*512, +512)
  const int z     = blockIdx.y;
  const int t = threadIdx.x;
  const float* xrow = x + ((size_t)(z*12 + 1))*4096;
  const int lo_in = opart*1024 - 7;        // ldin[i] = xrow[lo_in + i]
  for (int i = t; i < 1037; i += 256){
    const int pos = lo_in + i;
    ldin[i] = ((u32)pos < 4096u) ? xrow[pos] : 0.f;
  }
  __syncthreads();
  const int q = t >> 6, c = t & 63;
  float fw[15], pw[9];
#pragma unroll
  for (int k = 0; k < 15; k++) fw[k] = fwg[c*15 + k];
#pragma unroll
  for (int k = 0; k < 9;  k++) pw[k] = pwg[c*9 + k];
  const float fsc = fbn[c] / sqrtf(fbn[192+c] + 1e-5f);
  const float fsh = fbn[64+c] - fbn[128+c]*fsc;
  const float psc = pbn[c] / sqrtf(pbn[192+c] + 1e-5f);
  const float psh = pbn[64+c] - pbn[128+c]*psc;
  const float cbf = fbc[c], cbp = pbc[c];
  const int ob = q*128;                    // local output base for this thread
#pragma unroll
  for (int jp = 0; jp < 2; jp++){
    float pmx = -1e30f;
#pragma unroll
    for (int jf = 0; jf < 2; jf++){
      float fmx = -1e30f;
      for (int kk = 0; kk < 32; kk++){
        const int o = ob + jp*64 + jf*32 + kk;
        const float* s = &ldin[2*o];       // flut taps s[0..14]; pvc taps s[3..11]
        float fa = cbf;
#pragma unroll
        for (int k = 0; k < 15; k++) fa += fw[k]*s[k];
        fmx = fmaxf(fmx, lrelu_f(fa*fsc + fsh));
        float pa = cbp;
#pragma unroll
        for (int k = 0; k < 9;  k++) pa += pw[k]*s[3+k];
        pmx = fmaxf(pmx, lrelu_f(pa*psc + psh));
      }
      fp[(size_t)z*4096 + c*64 + opart*16 + q*4 + jp*2 + jf] = fmx;
    }
    pp[(size_t)z*2048 + c*32 + opart*8 + q*2 + jp] = pmx;
  }
}

// attention v3: one wave per (sample, head); K,V staged in LDS.
// qkv rows (64*nb, 768) fp32 -> o (64*nb, 256) bf16
__global__ __launch_bounds__(64) void attn3(const float* __restrict__ qkv, u16* __restrict__ o){
  const int bh = blockIdx.x;
  const int b = bh >> 3, h = bh & 7;
  __shared__ float Ks[2048], Vs[2048];
  const int t = threadIdx.x;
  for (int e = t; e < 2048; e += 64){
    const int r = e >> 5, c = e & 31;
    const size_t base = ((size_t)(b*64 + r))*768 + h*32 + c;
    Ks[e] = qkv[base + 256];
    Vs[e] = qkv[base + 512];
  }
  __syncthreads();
  float qv[32];
  const float* qp = qkv + ((size_t)(b*64 + t))*768 + h*32;
#pragma unroll
  for (int d = 0; d < 32; d++) qv[d] = qp[d];
  float s[64]; float mx = -1e30f;
  const float isq = 0.17677669529663687f;        // 1/sqrt(32)
  for (int kc = 0; kc < 64; kc++){
    const float* kr = &Ks[kc*32];
    float dot = 0.f;
#pragma unroll
    for (int d = 0; d < 32; d++) dot += qv[d]*kr[d];
    dot *= isq; s[kc] = dot; mx = fmaxf(mx, dot);
  }
  float sum = 0.f;
  for (int kc = 0; kc < 64; kc++){ float e = __expf(s[kc]-mx); s[kc] = e; sum += e; }
  const float inv = 1.0f/sum;
  float ov[32];
#pragma unroll
  for (int d = 0; d < 32; d++) ov[d] = 0.f;
  for (int kc = 0; kc < 64; kc++){
    const float* vr = &Vs[kc*32];
    const float wgt = s[kc];
#pragma unroll
    for (int d = 0; d < 32; d++) ov[d] += wgt*vr[d];
  }
  u16* op = o + ((size_t)(b*64 + t))*256 + h*32;
#pragma unroll
  for (int d = 0; d < 32; d++) op[d] = f2bf(ov[d]*inv);
}

__global__ void xmain_s(const float* __restrict__ om, float* __restrict__ xm, int b0){
  const int e = threadIdx.x, bl = blockIdx.x;
  float m = -1e30f;
  for (int s = 0; s < 64; s++) m = fmaxf(m, om[((size_t)(bl*64+s))*256 + e]);
  xm[(size_t)(b0+bl)*256 + e] = m;
}

// FC dot-product: one block per output scalar (b,j); float4 K-reduction.
template<int N, int K>
__global__ __launch_bounds__(256) void fcdot_kernel(const float* __restrict__ inp,
    const float* __restrict__ w, float* __restrict__ outp)
{
  const int b = blockIdx.x, j = blockIdx.y;
  const int t = threadIdx.x;
  const float4* x4 = (const float4*)(inp + (size_t)b*K);
  const float4* w4 = (const float4*)(w   + (size_t)j*K);
  float s = 0.f;
#pragma unroll
  for (int k = t; k < K/4; k += 256){
    const float4 a = x4[k], c = w4[k];
    s += a.x*c.x + a.y*c.y + a.z*c.z + a.w*c.w;
  }
  for (int o2 = 32; o2 > 0; o2 >>= 1) s += __shfl_down(s, o2, 64);
  __shared__ float red[4];
  const int wv = t >> 6, lane = t & 63;
  if (lane == 0) red[wv] = s;
  __syncthreads();
  if (t == 0) outp[(size_t)b*N + j] = lrelu_f(red[0]+red[1]+red[2]+red[3]);
}

// r18 DFT v2: block = (b, 8-bin chunk); row staged once in LDS; 8 lanes/bin
// with interleaved n-assignment (n = k*8+sub -> conflict-free, 8-way bcast);
// twiddle rotation recurrence; shfl_xor reduce within 8-lane groups.
__global__ __launch_bounds__(256) void fft2_kernel(const float* __restrict__ x, float* __restrict__ mag){
  __shared__ float row[4096];
  const int b = blockIdx.x, chunk = blockIdx.y;
  const int t = threadIdx.x;
  const float* xp = x + ((size_t)(b*12 + 1))*4096;
  for (int i = t; i < 4096; i += 256) row[i] = xp[i];
  __syncthreads();
  const int binl = t >> 3, sub = t & 7;
  const int bin = chunk*32 + binl + 50;
  const float C = 6.283185307179586f/4096.0f;
  float cr, si;  __sincosf((float)((bin*sub) & 4095)*C, &si, &cr);
  float cS, sS;  __sincosf((float)((bin*8)   & 4095)*C, &sS, &cS);
  float re = 0.f, im = 0.f;
  for (int k = 0; k < 512; k++){
    const float xv = row[(k<<3) + sub];
    re += xv*cr; im += xv*si;
    const float c2 = cr*cS - si*sS;
    si = cr*sS + si*cS;
    cr = c2;
  }
  re += __shfl_xor(re, 1, 8); im += __shfl_xor(im, 1, 8);
  re += __shfl_xor(re, 2, 8); im += __shfl_xor(im, 2, 8);
  re += __shfl_xor(re, 4, 8); im += __shfl_xor(im, 4, 8);
  if (sub == 0) mag[b*256 + chunk*32 + binl] = sqrtf(re*re + im*im);
}

__global__ void rowmax_kernel(const float* __restrict__ mag, float* __restrict__ rmax){
  const int b = blockIdx.x, t = threadIdx.x;
  __shared__ float r[256];
  r[t] = mag[b*256 + t]; __syncthreads();
  for (int o2 = 128; o2 > 0; o2 >>= 1){ if (t < o2) r[t] = fmaxf(r[t], r[t+o2]); __syncthreads(); }
  if (t == 0) rmax[b] = r[0];
}

__global__ void freq_kernel(const float* __restrict__ mag, const float* __restrict__ rmax,
                            const float* __restrict__ fw, const float* __restrict__ fb,
                            float* __restrict__ outp){
  const int b = blockIdx.x, j = threadIdx.x;  // 32
  const float mx = rmax[b];
  const float sc = mx > 0.f ? 1.0f/mx : 1.0f;
  float acc = fb[j];
  for (int i = 0; i < 256; i++) acc += (mag[b*256+i]*sc) * fw[(size_t)j*256 + i];
  outp[b*32 + j] = lrelu_f(acc);
}

__global__ void final_kernel(const float* __restrict__ xm, const float* __restrict__ l,
                             const float* __restrict__ fr, const float* __restrict__ fv,
                             const float* __restrict__ pv, const float* __restrict__ fcw,
                             const float* __restrict__ fcb, float* __restrict__ outp){
  const int b = blockIdx.x, j = threadIdx.x;  // 32 threads, 27 active
  if (j >= 27) return;
  float acc = fcb[j];
  const float* wr_ = fcw + (size_t)j*396;
  for (int i = 0; i < 256; i++) acc += xm[b*256+i] * wr_[i];
  for (int i = 0; i < 12;  i++) acc += l[b*12+i]   * wr_[256+i];
  for (int i = 0; i < 32;  i++) acc += fr[b*32+i]  * wr_[268+i];
  for (int i = 0; i < 64;  i++) acc += fv[b*64+i]  * wr_[300+i];
  for (int i = 0; i < 32;  i++) acc += pv[b*32+i]  * wr_[364+i];
  outp[b*27 + j] = acc;
  outp[64*27 + b*27 + j] = 1.0f/(1.0f + __expf(-acc));
}

// --------------------------- host side --------------------------------------
extern "C" void kernel_launch(void* const* d_in, const int* in_sizes, int n_in,
                              void* d_out, int out_size, void* d_ws, size_t ws_size,
                              hipStream_t stream)
{
  const float* x       = (const float*)d_in[0];
  const float* l       = (const float*)d_in[1];
  const float* conv_w  = (const float*)d_in[2];
  const float* bn0     = (const float*)d_in[3];
  const float* rb_c1   = (const float*)d_in[4];
  const float* rb_bn1  = (const float*)d_in[5];
  const float* rb_c2   = (const float*)d_in[6];
  const float* rb_bn2  = (const float*)d_in[7];
  const float* rb_id   = (const float*)d_in[8];
  const float* in_w    = (const float*)d_in[9];
  const float* in_b    = (const float*)d_in[10];
  const float* out_w   = (const float*)d_in[11];
  const float* out_b   = (const float*)d_in[12];
  const float* flut_w  = (const float*)d_in[13];
  const float* flut_b  = (const float*)d_in[14];
  const float* flut_bn = (const float*)d_in[15];
  const float* pvc_w   = (const float*)d_in[16];
  const float* pvc_b   = (const float*)d_in[17];
  const float* pvc_bn  = (const float*)d_in[18];
  const float* w_flut2 = (const float*)d_in[19];
  const float* w_pvc2  = (const float*)d_in[20];
  const float* freq_w  = (const float*)d_in[21];
  const float* freq_b  = (const float*)d_in[22];
  const float* fc_w    = (const float*)d_in[23];
  const float* fc_b    = (const float*)d_in[24];
  float* outp = (float*)d_out;

  char* ws = (char*)d_ws;
  size_t off = 0;
  auto alloc = [&](size_t bytes)->char*{ char* p = ws + off; off = (off + bytes + 255) & ~(size_t)255; return p; };

  // ---- persistent (~16.7 MiB) ----
  u16* wr    = (u16*)alloc((size_t)10*589824*2);   // 11.25 MiB res weights [slot][co][tap*256+ci]
  u16* wid   = (u16*)alloc((size_t)5*131072*2);    //  1.25 MiB identity 2-tap weights
  u16* w0p   = (u16*)alloc(131072);                //  conv0 weights, K-padded
  u16* wqkvb = (u16*)alloc(196608*2);              //  qkv proj weights bf16 (768,256)
  u16* woutb = (u16*)alloc(65536*2);               //  out proj weights bf16 (256,256)
  u16* h5b   = (u16*)alloc((size_t)64*64*256*2);   //  2 MiB (B*64,256) bf16
  u16* zbuf  = (u16*)alloc(256);                   //  16B+ zero page for OOB-tap clamp
  float* s0 = (float*)alloc(1024);  float* b0 = (float*)alloc(1024);
  float* s1 = (float*)alloc(5120);  float* b1 = (float*)alloc(5120);
  float* s2 = (float*)alloc(5120);  float* b2 = (float*)alloc(5120);
  float* xm    = (float*)alloc(65536);
  float* fpool = (float*)alloc((size_t)64*4096*4); // 1 MiB
  float* ppool = (float*)alloc((size_t)64*2048*4); // 0.5 MiB
  float* mag   = (float*)alloc(65536);
  float* rmax  = (float*)alloc(1024);
  float* fvecv = (float*)alloc(16384);
  float* pvecv = (float*)alloc(8192);
  float* freqv = (float*)alloc(8192);

  // ---- adaptive batch slice: chain arena = 2.625*sp MiB (bf16 activations) ----
  const size_t rem = (ws_size > off) ? (ws_size - off) : 0;
  int sp = 0;
  for (int c = 64; c >= 2; c >>= 1)
    if ((size_t)c*2752512 + (1<<20) <= rem){ sp = c; break; }
  if (sp == 0){ canary_kernel<<<14,256,0,stream>>>(outp); return; }

  u16* x16q = (u16*)alloc((size_t)sp*131072);      // (sp,4096,16) bf16
  u16* h0q  = (u16*)alloc((size_t)sp*1048576);     // (sp,2048,256) bf16
  u16* hCq  = (u16*)alloc((size_t)sp*524288);      // (sp,<=1024,256) bf16
  u16* ping = (u16*)alloc((size_t)sp*524288);
  u16* pong = (u16*)alloc((size_t)sp*524288);

  // ---- param prep (once) ----
  zerok_kernel<<<1,128,0,stream>>>(zbuf);
  bnfold_kernel<<<11,256,0,stream>>>(bn0, rb_bn1, rb_bn2, s0,b0,s1,b1,s2,b2);
  w0prep_kernel<<<256,256,0,stream>>>(conv_w, w0p);
  wrprep_kernel<<<dim3(256,10),256,0,stream>>>(rb_c1, rb_c2, wr);
  widprep_kernel<<<dim3(256,5),256,0,stream>>>(rb_id, wid);
  castb_kernel<<<768,256,0,stream>>>(in_w, wqkvb, 196608);
  castb_kernel<<<256,256,0,stream>>>(out_w, woutb, 65536);

  // ---- res chain: conv0 on gemm_conv; i=0 on gemm8; i=1 on gemm_conv;
  //      i>=2 on gemm_sm 64x128 tiles (r24: fills idle CUs at small layers) ----
  for (int s = 0; s < 64/sp; s++){
    const float* xs = x + (size_t)s*sp*49152;
    x16prep_kernel<<<dim3(16,sp),256,0,stream>>>(xs, x16q);
    // conv0: (sp,4096,16) -> (sp,2048,256), k=15 s=2 p=7, K padded to 256
    {
      const int mm = sp*16, nn = 2;
      gemm_conv<true,false,false><<<mm*nn,256,0,stream>>>(
          x16q - 112, w0p, nullptr, nullptr, h0q, s0, b0,
          256, 0, 11, 2, 4, 7, 4096, 65536, 32, 0, 0, 256, 256, 1, mm, nn);
    }
    int Lin = 2048;
    const u16* bin = h0q;
    for (int i = 0; i < 5; i++){
      const int Lo = Lin >> 1;
      const int lgLo = 10 - i;
      if (i < 1){
        // 8-phase 256x256 path (grid 256 blocks = 1 block/CU at sp=64)
        const int mb = sp*Lo/256;
        gemm8<false><<<mb,512,0,stream>>>(
            bin - 1024, wr + (size_t)i*589824, nullptr, nullptr, hCq, s1+i*256, b1+i*256, zbuf,
            2304, 0, lgLo, 2, 8, 4, Lin, Lin*256, 512, 0, 0);
        u16* bout = (i&1) ? pong : ping;
        gemm8<true><<<mb,512,0,stream>>>(
            hCq - 1024, wr + (size_t)(5+i)*589824, bin, wid + (size_t)i*131072,
            bout, s2+i*256, b2+i*256, zbuf,
            2304, 512, lgLo, 1, 8, 4, Lo, Lo*256, 256, Lin*256, 512);
        bin = bout;
      } else if (i == 1){
        // 128^2 kernel (512-block grid, 2/CU TLP)
        const int mm = sp*Lo/128, nn = 2;
        gemm_conv<true,false,false><<<mm*nn,256,0,stream>>>(
            bin - 1024, wr + (size_t)i*589824, nullptr, nullptr, hCq, s1+i*256, b1+i*256,
            2304, 0, lgLo, 2, 8, 4, Lin, Lin*256, 512, 0, 0, 256, 256, 1, mm, nn);
        u16* bout = (i&1) ? pong : ping;
        gemm_conv<true,true,false><<<mm*nn,256,0,stream>>>(
            hCq - 1024, wr + (size_t)(5+i)*589824, bin, wid + (size_t)i*131072,
            bout, s2+i*256, b2+i*256,
            2304, 512, lgLo, 1, 8, 4, Lo, Lo*256, 256, Lin*256, 512, 256, 256, 1, mm, nn);
        bin = bout;
      } else {
        // i>=2: 64x128 tiles double the grid (r24)
        const int mm = sp*Lo/64, nn = 2;
        gemm_sm<true,false,false><<<mm*nn,256,0,stream>>>(
            bin - 1024, wr + (size_t)i*589824, nullptr, nullptr, hCq, s1+i*256, b1+i*256,
            2304, 0, lgLo, 2, 8, 4, Lin, Lin*256, 512, 0, 0, 256, 256, 1, mm, nn);
        if (i < 4){
          u16* bout = (i&1) ? pong : ping;
          gemm_sm<true,true,false><<<mm*nn,256,0,stream>>>(
              hCq - 1024, wr + (size_t)(5+i)*589824, bin, wid + (size_t)i*131072,
              bout, s2+i*256, b2+i*256,
              2304, 512, lgLo, 1, 8, 4, Lo, Lo*256, 256, Lin*256, 512, 256, 256, 1, mm, nn);
          bin = bout;
        } else {
          gemm_sm<true,true,false><<<mm*nn,256,0,stream>>>(
              hCq - 1024, wr + (size_t)(5+i)*589824, bin, wid + (size_t)i*131072,
              h5b + (size_t)s*sp*16384, s2+i*256, b2+i*256,
              2304, 512, lgLo, 1, 8, 4, Lo, Lo*256, 256, Lin*256, 512, 256, 256, 1, mm, nn);
        }
      }
      Lin = Lo;
    }
  }

  // ---- MHA on MFMA GEMMs; slice if arena is small ----
  {
    const int nsl = (sp >= 8) ? 1 : 4;
    const int rows = 4096/nsl;                       // 64*samples per slice
    float* qkvF = (float*)x16q;                      // arena aliases (chain is dead)
    u16*   o_b  = (u16*)(qkvF + (size_t)rows*768);
    float* omF  = (float*)(o_b + (size_t)rows*256);
    for (int s = 0; s < nsl; s++){
      const int mm = rows/128;
      gemm_conv<false,false,true><<<mm*6,256,0,stream>>>(
          h5b + (size_t)s*rows*256, wqkvb, nullptr, nullptr, qkvF, nullptr, in_b,
          256, 0, 12, 1, 8, 0, 0, 0, 256, 0, 0, 768, 768, 0, mm, 6);
      attn3<<<(rows/64)*8,64,0,stream>>>(qkvF, o_b);
      gemm_conv<false,false,true><<<mm*2,256,0,stream>>>(
          o_b, woutb, nullptr, nullptr, omF, nullptr, out_b,
          256, 0, 12, 1, 8, 0, 0, 0, 256, 0, 0, 256, 256, 0, mm, 2);
      xmain_s<<<rows/64,256,0,stream>>>(omF, xm, s*(rows/64));
    }
  }

  // ---- lead_II branch: single fused kernel (conv+bn+lrelu+pool x2) ----
  leadii_fused<<<dim3(4,64),256,0,stream>>>(x, flut_w, flut_b, flut_bn,
                                            pvc_w, pvc_b, pvc_bn, fpool, ppool);
  fcdot_kernel<64,4096><<<dim3(64,64),256,0,stream>>>(fpool, w_flut2, fvecv);
  fcdot_kernel<32,2048><<<dim3(64,32),256,0,stream>>>(ppool, w_pvc2, pvecv);

  // ---- FFT branch (LDS-staged DFT) ----
  fft2_kernel<<<dim3(64,8),256,0,stream>>>(x, mag);
  rowmax_kernel<<<64,256,0,stream>>>(mag, rmax);
  freq_kernel<<<64,32,0,stream>>>(mag, rmax, freq_w, freq_b, freqv);

  // ---- combine + logits + sigmoid ----
  final_kernel<<<64,32,0,stream>>>(xm, l, freqv, fvecv, pvecv, fc_w, fc_b, outp);
  (void)in_sizes; (void)n_in; (void)out_size;
}

// Round 13
// 944.850 us; speedup vs baseline: 1.1258x; 1.0431x over previous
//
#include <hip/hip_runtime.h>

typedef unsigned short u16;
typedef unsigned int   u32;
typedef __attribute__((ext_vector_type(8))) short short8;   // 8 x bf16 (4 VGPRs)
typedef __attribute__((ext_vector_type(4))) float f32x4;    // MFMA accumulator

__device__ __forceinline__ float bf2f(u16 u){ return __uint_as_float(((u32)u)<<16); }
__device__ __forceinline__ u16 f2bf(float f){ u32 x = __float_as_uint(f); x += 0x7fffu + ((x>>16)&1u); return (u16)(x>>16); }
__device__ __forceinline__ float lrelu_f(float v){ return v >= 0.0f ? v : 0.01f*v; }

#if defined(__has_builtin)
#if __has_builtin(__builtin_amdgcn_global_load_lds)
#define HAS_GLL 1
#endif
#endif
#ifndef HAS_GLL
#define HAS_GLL 0
#endif

// async global->LDS DMA, 16B per lane; LDS dst = l + lane*16 (wave-uniform l).
// Defined unconditionally: host pass lacks the builtin (__has_builtin false on
// host target), so it gets a parse-only stub; device pass on gfx950 uses DMA.
__device__ __forceinline__ void gll16(const u16* g, u16* l){
#if HAS_GLL
  __builtin_amdgcn_global_load_lds(
      (__attribute__((address_space(1))) void*)(void*)g,
      (__attribute__((address_space(3))) void*)l, 16, 0, 0);
#else
  *(uint4*)l = *(const uint4*)g;   // never executed on gfx950; host-parse stub
#endif
}

// compiler-level memory fence around the HW barrier: prevents LDS/VMEM ops
// migrating across; MFMA/VALU may still move (harmless).
#define SBAR() { asm volatile("" ::: "memory"); __builtin_amdgcn_s_barrier(); asm volatile("" ::: "memory"); }
#define VMW(N) asm volatile("s_waitcnt vmcnt(" #N ")" ::: "memory")

// ---------------------------------------------------------------------------
// Implicit-GEMM conv (PROVEN r10/r12 config — conv0, MHA):
// Tile 128x128, BK=64, 4 waves x (4x4 of 16x16x32 bf16 MFMA), single acc,
// XOR-swizzled LDS, global_load_lds fast path, XCD-aware 1D grid decode.
// ---------------------------------------------------------------------------
template<bool PRED1, bool DUAL, bool F32OUT>
__global__ __launch_bounds__(256, 4) void gemm_conv(
    const u16* __restrict__ A1, const u16* __restrict__ B1,
    const u16* __restrict__ A2, const u16* __restrict__ B2,
    void* __restrict__ Out, const float* __restrict__ scale,
    const float* __restrict__ bias,
    int K1, int K2, int lgLo, int S1, int lgCin1, int P1, int Lin1,
    int Abatch1, int Arow1, int Abatch2, int Arow2,
    int Ncols, int Cout, int lrelu, int Mblks, int Nblks)
{
  __shared__ u16 ldsA[128*64];
  __shared__ u16 ldsB[128*64];
  const int tid = threadIdx.x;
  int nblk, mblk;
  {
    const int bid = blockIdx.x;
    if (Mblks & 7){ nblk = bid % Nblks; mblk = bid / Nblks; }
    else { const int grp = Nblks*8; const int g = bid/grp; const int r = bid - g*grp;
           nblk = r >> 3; mblk = g*8 + (r & 7); }
  }
  const int wv = tid >> 6, lane = tid & 63;
  const int mbase = (wv & 1)*64, nbase = (wv >> 1)*64;
  const int lq = lane >> 4, lm = lane & 15;
  const int sw = lm & 7;                            // fragment-read swizzle key

  f32x4 acc[4][4];
#pragma unroll
  for (int a_=0;a_<4;a_++)
#pragma unroll
    for (int b_=0;b_<4;b_++) acc[a_][b_] = (f32x4){0.f,0.f,0.f,0.f};

  float scv[4], biv[4];
  if constexpr (DUAL){
#pragma unroll
    for (int nt=0;nt<4;nt++){
      const int colg = nblk*128 + nbase + nt*16 + lm;   // DUAL: Ncols==Cout==256, in-range
      scv[nt] = scale[colg]; biv[nt] = bias[colg];
    }
  }

  auto mfma_step = [&](){
#pragma unroll
    for (int kk=0; kk<2; kk++){
      const int s8 = (((kk*4+lq) ^ sw) << 3);
      short8 af[4], bfr[4];
#pragma unroll
      for (int mt=0;mt<4;mt++) af[mt]  = *(const short8*)&ldsA[(mbase+mt*16+lm)*64 + s8];
#pragma unroll
      for (int nt=0;nt<4;nt++) bfr[nt] = *(const short8*)&ldsB[(nbase+nt*16+lm)*64 + s8];
#pragma unroll
      for (int mt=0;mt<4;mt++)
#pragma unroll
        for (int nt=0;nt<4;nt++)
          acc[mt][nt] = __builtin_amdgcn_mfma_f32_16x16x32_bf16(af[mt], bfr[nt], acc[mt][nt], 0,0,0);
    }
  };
  auto xform = [&](){                     // in-place epilogue at phase boundary
#pragma unroll
    for (int mt=0;mt<4;mt++)
#pragma unroll
      for (int nt=0;nt<4;nt++)
#pragma unroll
        for (int r=0;r<4;r++){
          float v = acc[mt][nt][r]*scv[nt] + biv[nt];
          acc[mt][nt][r] = lrelu ? lrelu_f(v) : v;
        }
  };

  const int Ktot = DUAL ? (K1 + K2) : K1;

  // wave-uniform interior test: unpredicated A reads for the whole m-tile?
  bool fast = (HAS_GLL != 0);
  if (PRED1 && fast){
    const int Lo = 1 << lgLo;
    if (Lo < 128) fast = false;
    else {
      const int lo0 = (mblk*128) & (Lo-1);
      const int taps = K1 >> lgCin1;
      fast = (lo0*S1 - P1 >= 0) && ((lo0+127)*S1 + taps - 1 - P1 < Lin1);
    }
  }

#if HAS_GLL
  if (fast){
    // Fast path: Lo>=128, tiles 128-aligned -> z constant per tile.
    const int pm0 = mblk*128;
    const int z0  = pm0 >> lgLo;
    const int lo0 = pm0 & ((1<<lgLo)-1);
    const int lr  = lane >> 3;
    const int lc8 = (lane & 7) ^ lr;              // swizzled chunk for this lane
    const u16* pA = A1 + (long)z0*Abatch1 + (long)(lo0 + wv*32 + lr)*Arow1 + lc8*8;
    const u16* pB = B1 + (long)(nblk*128 + wv*32 + lr)*K1 + lc8*8;
    long strA = Arow1, strB = K1;
    u16* da = &ldsA[(wv*32)*64];
    u16* db = &ldsB[(wv*32)*64];
    for (int k0 = 0; k0 < Ktot; k0 += 64){
      int kk = k0;
      if constexpr (DUAL){
        if (k0 >= K1){
          if (k0 == K1){
            pA = A2 + (long)z0*Abatch2 + (long)(lo0 + wv*32 + lr)*Arow2 + lc8*8;
            pB = B2 + (long)(nblk*128 + wv*32 + lr)*K2 + lc8*8;
            strA = Arow2; strB = K2;
          }
          kk = k0 - K1;
        }
      }
      __syncthreads();
#pragma unroll
      for (int u=0; u<4; u++) gll16(pA + (long)u*8*strA + kk, da + u*8*64);
#pragma unroll
      for (int u=0; u<4; u++) gll16(pB + (long)u*8*strB + kk, db + u*8*64);
      __syncthreads();      // drains DMA -> writes visible
      if constexpr (DUAL){ if (k0 == K1) xform(); }
      mfma_step();
    }
  } else
#endif
  {
    // predicated VGPR staging (zero-fills OOB taps), swizzled layout
    const int sr  = tid >> 1;
    const int cg  = (tid & 1)*4;
    const int pmS = mblk*128 + sr;
    const int zS  = pmS >> lgLo;
    const int loS = pmS & ((1<<lgLo)-1);
    const long aoff1 = (long)zS*Abatch1 + (long)loS*Arow1;
    long aoff2 = 0;
    if constexpr (DUAL) aoff2 = (long)zS*Abatch2 + (long)loS*Arow2;
    const int coS = nblk*128 + sr;
    const long boff1 = (long)coS*K1;
    long boff2 = 0;
    if constexpr (DUAL) boff2 = (long)coS*K2;
    const int ssw = sr & 7;

    for (int k0 = 0; k0 < Ktot; k0 += 64){
      const bool ph1 = !DUAL || (k0 < K1);
      __syncthreads();
      {
        const u16* asrc = ph1 ? (A1 + aoff1 + k0) : (A2 + aoff2 + (k0 - K1));
#pragma unroll
        for (int u=0; u<4; u++){
          const int c = cg + u;
          uint4 v; v.x=0u; v.y=0u; v.z=0u; v.w=0u;
          bool ok = true;
          if (PRED1 && ph1){
            int tap = (k0 + c*8) >> lgCin1;
            int pos = loS*S1 + tap - P1;
            ok = ((u32)pos < (u32)Lin1);
          }
          if (ok) v = *(const uint4*)(asrc + c*8);
          *(uint4*)&ldsA[sr*64 + ((c ^ ssw)*8)] = v;
        }
      }
      {
        const u16* bsrc = ph1 ? (B1 + boff1 + k0) : (B2 + boff2 + (k0 - K1));
#pragma unroll
        for (int u=0; u<4; u++){
          const int c = cg + u;
          uint4 v = *(const uint4*)(bsrc + c*8);
          *(uint4*)&ldsB[sr*64 + ((c ^ ssw)*8)] = v;
        }
      }
      __syncthreads();
      if constexpr (DUAL){ if (k0 == K1) xform(); }
      mfma_step();
    }
  }

  // epilogue: DUAL acc is already final (transform applied at boundary + id)
#pragma unroll
  for (int nt=0;nt<4;nt++){
    const int colg = nblk*128 + nbase + nt*16 + lm;
    if (colg >= Ncols) continue;
    float sc = 1.0f, bi = 0.0f;
    if constexpr (!DUAL){
      if (scale) sc = scale[colg];
      if (bias)  bi = bias[colg];
    }
#pragma unroll
    for (int mt=0;mt<4;mt++){
#pragma unroll
      for (int r=0;r<4;r++){
        const long pm = (long)mblk*128 + mbase + mt*16 + lq*4 + r;
        float v = acc[mt][nt][r];
        if constexpr (!DUAL){
          v = v*sc + bi;
          if (lrelu) v = lrelu_f(v);
        }
        if constexpr (F32OUT) ((float*)Out)[pm*Cout + colg] = v;
        else                  ((u16*)Out)[pm*Cout + colg] = f2bf(v);
      }
    }
  }
}

// ---------------------------------------------------------------------------
// r24/r26: 64x128-tile sibling (gemm_sm) for deep layers i>=1. MEASURED (R12):
// at i>=2 this saved ~70 us vs 128^2 tiles — the occupancy mechanism (more
// blocks/CU hiding per-block latency serialization) dominates the extra
// L2-resident B re-reads. r26 extends it to i=1 (1024 blocks = 4/CU vs 2/CU).
// Same 2-barrier loop, same XOR-swizzle, same gll fast path / pred fallback.
// 4 waves each own 64 rows x 32 cols (acc[4][2]); LDS 24 KiB.
// ---------------------------------------------------------------------------
template<bool PRED1, bool DUAL, bool F32OUT>
__global__ __launch_bounds__(256, 4) void gemm_sm(
    const u16* __restrict__ A1, const u16* __restrict__ B1,
    const u16* __restrict__ A2, const u16* __restrict__ B2,
    void* __restrict__ Out, const float* __restrict__ scale,
    const float* __restrict__ bias,
    int K1, int K2, int lgLo, int S1, int lgCin1, int P1, int Lin1,
    int Abatch1, int Arow1, int Abatch2, int Arow2,
    int Ncols, int Cout, int lrelu, int Mblks, int Nblks)
{
  __shared__ u16 ldsA[64*64];
  __shared__ u16 ldsB[128*64];
  const int tid = threadIdx.x;
  int nblk, mblk;
  {
    const int bid = blockIdx.x;
    if (Mblks & 7){ nblk = bid % Nblks; mblk = bid / Nblks; }
    else { const int grp = Nblks*8; const int g = bid/grp; const int r = bid - g*grp;
           nblk = r >> 3; mblk = g*8 + (r & 7); }
  }
  const int wv = tid >> 6, lane = tid & 63;
  const int lq = lane >> 4, lm = lane & 15;
  const int sw = lm & 7;

  f32x4 acc[4][2];
#pragma unroll
  for (int a_=0;a_<4;a_++)
#pragma unroll
    for (int b_=0;b_<2;b_++) acc[a_][b_] = (f32x4){0.f,0.f,0.f,0.f};

  float scv[2], biv[2];
  if constexpr (DUAL){
#pragma unroll
    for (int nt=0;nt<2;nt++){
      const int colg = nblk*128 + wv*32 + nt*16 + lm;
      scv[nt] = scale[colg]; biv[nt] = bias[colg];
    }
  }

  auto mfma_step = [&](){
#pragma unroll
    for (int kk=0; kk<2; kk++){
      const int s8 = (((kk*4+lq) ^ sw) << 3);
      short8 af[4], bfr[2];
#pragma unroll
      for (int mt=0;mt<4;mt++) af[mt]  = *(const short8*)&ldsA[(mt*16+lm)*64 + s8];
#pragma unroll
      for (int nt=0;nt<2;nt++) bfr[nt] = *(const short8*)&ldsB[(wv*32+nt*16+lm)*64 + s8];
#pragma unroll
      for (int mt=0;mt<4;mt++)
#pragma unroll
        for (int nt=0;nt<2;nt++)
          acc[mt][nt] = __builtin_amdgcn_mfma_f32_16x16x32_bf16(af[mt], bfr[nt], acc[mt][nt], 0,0,0);
    }
  };
  auto xform = [&](){
#pragma unroll
    for (int mt=0;mt<4;mt++)
#pragma unroll
      for (int nt=0;nt<2;nt++)
#pragma unroll
        for (int r=0;r<4;r++){
          float v = acc[mt][nt][r]*scv[nt] + biv[nt];
          acc[mt][nt][r] = lrelu ? lrelu_f(v) : v;
        }
  };

  const int Ktot = DUAL ? (K1 + K2) : K1;

  // wave-uniform interior test for the 64-row m-tile
  bool fast = (HAS_GLL != 0);
  if (PRED1 && fast){
    const int Lo = 1 << lgLo;
    if (Lo < 64) fast = false;
    else {
      const int lo0 = (mblk*64) & (Lo-1);
      const int taps = K1 >> lgCin1;
      fast = (lo0*S1 - P1 >= 0) && ((lo0+63)*S1 + taps - 1 - P1 < Lin1);
    }
  }

#if HAS_GLL
  if (fast){
    const int pm0 = mblk*64;
    const int z0  = pm0 >> lgLo;
    const int lo0 = pm0 & ((1<<lgLo)-1);
    const int lr  = lane >> 3;
    const int lc8 = (lane & 7) ^ lr;              // swizzled chunk (row&7 == lr)
    const u16* pA = A1 + (long)z0*Abatch1 + (long)(lo0 + wv*16 + lr)*Arow1 + lc8*8;
    const u16* pB = B1 + (long)(nblk*128 + wv*32 + lr)*K1 + lc8*8;
    long strA = Arow1, strB = K1;
    u16* da = &ldsA[(wv*16)*64];
    u16* db = &ldsB[(wv*32)*64];
    for (int k0 = 0; k0 < Ktot; k0 += 64){
      int kk = k0;
      if constexpr (DUAL){
        if (k0 >= K1){
          if (k0 == K1){
            pA = A2 + (long)z0*Abatch2 + (long)(lo0 + wv*16 + lr)*Arow2 + lc8*8;
            pB = B2 + (long)(nblk*128 + wv*32 + lr)*K2 + lc8*8;
            strA = Arow2; strB = K2;
          }
          kk = k0 - K1;
        }
      }
      __syncthreads();
#pragma unroll
      for (int u=0; u<2; u++) gll16(pA + (long)u*8*strA + kk, da + u*8*64);
#pragma unroll
      for (int u=0; u<4; u++) gll16(pB + (long)u*8*strB + kk, db + u*8*64);
      __syncthreads();
      if constexpr (DUAL){ if (k0 == K1) xform(); }
      mfma_step();
    }
  } else
#endif
  {
    // predicated VGPR staging: A 64 rows (4 thr/row x 2 chunks), B 128 rows
    const int srA = tid >> 2;                    // 0..63
    const int cgA = (tid & 3)*2;                 // 0,2,4,6
    const int pmS = mblk*64 + srA;
    const int zS  = pmS >> lgLo;
    const int loS = pmS & ((1<<lgLo)-1);
    const long aoff1 = (long)zS*Abatch1 + (long)loS*Arow1;
    long aoff2 = 0;
    if constexpr (DUAL) aoff2 = (long)zS*Abatch2 + (long)loS*Arow2;
    const int sswA = srA & 7;
    const int srB = tid >> 1;                    // 0..127
    const int cgB = (tid & 1)*4;
    const int coS = nblk*128 + srB;
    const long boff1 = (long)coS*K1;
    long boff2 = 0;
    if constexpr (DUAL) boff2 = (long)coS*K2;
    const int sswB = srB & 7;

    for (int k0 = 0; k0 < Ktot; k0 += 64){
      const bool ph1 = !DUAL || (k0 < K1);
      __syncthreads();
      {
        const u16* asrc = ph1 ? (A1 + aoff1 + k0) : (A2 + aoff2 + (k0 - K1));
#pragma unroll
        for (int u=0; u<2; u++){
          const int c = cgA + u;
          uint4 v; v.x=0u; v.y=0u; v.z=0u; v.w=0u;
          bool ok = true;
          if (PRED1 && ph1){
            int tap = (k0 + c*8) >> lgCin1;
            int pos = loS*S1 + tap - P1;
            ok = ((u32)pos < (u32)Lin1);
          }
          if (ok) v = *(const uint4*)(asrc + c*8);
          *(uint4*)&ldsA[srA*64 + ((c ^ sswA)*8)] = v;
        }
      }
      {
        const u16* bsrc = ph1 ? (B1 + boff1 + k0) : (B2 + boff2 + (k0 - K1));
#pragma unroll
        for (int u=0; u<4; u++){
          const int c = cgB + u;
          uint4 v = *(const uint4*)(bsrc + c*8);
          *(uint4*)&ldsB[srB*64 + ((c ^ sswB)*8)] = v;
        }
      }
      __syncthreads();
      if constexpr (DUAL){ if (k0 == K1) xform(); }
      mfma_step();
    }
  }

#pragma unroll
  for (int nt=0;nt<2;nt++){
    const int colg = nblk*128 + wv*32 + nt*16 + lm;
    if (colg >= Ncols) continue;
    float sc = 1.0f, bi = 0.0f;
    if constexpr (!DUAL){
      if (scale) sc = scale[colg];
      if (bias)  bi = bias[colg];
    }
#pragma unroll
    for (int mt=0;mt<4;mt++){
#pragma unroll
      for (int r=0;r<4;r++){
        const long pm = (long)mblk*64 + mt*16 + lq*4 + r;
        float v = acc[mt][nt][r];
        if constexpr (!DUAL){
          v = v*sc + bi;
          if (lrelu) v = lrelu_f(v);
        }
        if constexpr (F32OUT) ((float*)Out)[pm*Cout + colg] = v;
        else                  ((u16*)Out)[pm*Cout + colg] = f2bf(v);
      }
    }
  }
}

// ---------------------------------------------------------------------------
// r21/r22/r23: 256x256 engine, two-barrier deep-prefetch KTILE (measured-best).
// Engine placement (measured): gemm8 ONLY for i=0; gemm_conv for conv0 + MHA;
// gemm_sm for i>=1 (r26). gemm8 structure iteration CLOSED.
// ---------------------------------------------------------------------------
#define RDA(BUF, MH) {                                                     \
  _Pragma("unroll") for (int mt=0; mt<4; mt++)                             \
  _Pragma("unroll") for (int kk=0; kk<2; kk++)                             \
    Ar[mt][kk] = *(const short8*)&ldsA[BUF][(((wr<<7) + (((MH)*4+mt)<<4) + lm)<<6) + (((kk*4+lq)^sw)<<3)]; }
#define RDB(BUF, NH, RB) {                                                 \
  _Pragma("unroll") for (int nt=0; nt<2; nt++)                             \
  _Pragma("unroll") for (int kk=0; kk<2; kk++)                             \
    RB[nt][kk] = *(const short8*)&ldsB[BUF][(((wc<<6) + (((NH)*2+nt)<<4) + lm)<<6) + (((kk*4+lq)^sw)<<3)]; }
#define MME(MH, NH, RB) {                                                  \
  __builtin_amdgcn_s_setprio(1);                                           \
  _Pragma("unroll") for (int mt=0; mt<4; mt++)                             \
  _Pragma("unroll") for (int nt=0; nt<2; nt++)                             \
  _Pragma("unroll") for (int kk=0; kk<2; kk++)                             \
    acc[(MH)*4+mt][(NH)*2+nt] = __builtin_amdgcn_mfma_f32_16x16x32_bf16(   \
        Ar[mt][kk], RB[nt][kk], acc[(MH)*4+mt][(NH)*2+nt], 0,0,0);         \
  __builtin_amdgcn_s_setprio(0); }

// One K-tile = 4 phases. Stages target tile G+2 (same BUF), each slot staged
// immediately after its last ds_read retired (enforced by the barrier pair of
// the phase where it was read). vmcnt(8) at P4 = tile G+1 fully landed (its 8
// loads were issued in iteration G-1, >=4 phases ago); in-flight = tile G+2.
#define KTILE(G, BUF) {                                                    \
  if constexpr (DUAL){ if ((G) == t1) xf(); }                              \
  /* P1: A-ev + B-ev of tile G */                                          \
  RDA(BUF, 0); RDB(BUF, 0, Br0);                                           \
  SBAR(); MME(0,0,Br0); SBAR();                                            \
  /* P2: B-od of tile G; stage A-ev(G+2) (slot freed by P1 barrier) */     \
  RDB(BUF, 1, Br1);                                                        \
  if ((G)+2 < nT) stA((G)+2, 0);                                           \
  SBAR(); MME(0,1,Br1); SBAR();                                            \
  /* P3: A-od of tile G; stage B-ev+B-od(G+2) (freed P1/P2) */             \
  RDA(BUF, 1);                                                             \
  if ((G)+2 < nT){ stB((G)+2, 0); stB((G)+2, 1); }                         \
  SBAR(); MME(1,0,Br0); SBAR();                                            \
  /* P4: stage A-od(G+2) (freed P3); counted wait for tile G+1 */          \
  if ((G)+2 < nT) stA((G)+2, 1);                                           \
  SBAR(); MME(1,1,Br1);                                                    \
  if ((G)+2 < nT) { VMW(8); } else { VMW(0); }                             \
  SBAR(); }

template<bool DUAL>
__global__ __launch_bounds__(512, 2) void gemm8(
    const u16* __restrict__ A1, const u16* __restrict__ B1,
    const u16* __restrict__ A2, const u16* __restrict__ B2,
    u16* __restrict__ Out, const float* __restrict__ scale,
    const float* __restrict__ bias, const u16* __restrict__ zb,
    int K1, int K2, int lgLo, int S1, int lgCin1, int P1, int Lin1,
    int Abatch1, int Arow1, int Abatch2, int Arow2)
{
  __shared__ u16 ldsA[2][16384];     // [buf][256 rows][64]
  __shared__ u16 ldsB[2][16384];

  const int tid  = threadIdx.x;
  const int wv   = tid >> 6, lane = tid & 63;
  const int wr   = wv >> 2, wc = wv & 3;
  const int lq   = lane >> 4, lm = lane & 15, sw = lm & 7;
  const int lr   = lane >> 3;
  const int cG   = (lane & 7) ^ lr;                 // pre-swizzled global chunk

  const int pm0 = blockIdx.x << 8;
  const int z0  = pm0 >> lgLo;
  const int lo0 = pm0 & ((1 << lgLo) - 1);

  const u16* baA1 = A1 + (long)z0*Abatch1 + (long)(lo0 + lr)*Arow1 + cG*8;
  const u16* baB1 = B1 + (long)lr*K1 + cG*8;
  const u16* baA2 = nullptr; const u16* baB2 = nullptr;
  if constexpr (DUAL){
    baA2 = A2 + (long)z0*Abatch2 + (long)(lo0 + lr)*Arow2 + cG*8;
    baB2 = B2 + (long)lr*K2 + cG*8;
  }
  const int posL = (lo0 + lr)*S1 - P1;              // per-lane pos base
  const int nT = (DUAL ? (K1 + K2) : K1) >> 6;
  const int t1 = DUAL ? (K1 >> 6) : 0x7fffffff;

  // block-uniform: no A tap can fall outside [0, Lin1) for this m-tile?
  bool interior;
  {
    const int taps = K1 >> lgCin1;
    interior = (lo0*S1 - P1 >= 0) && ((lo0+255)*S1 + taps - 1 - P1 < Lin1);
  }

  f32x4 acc[8][4];
#pragma unroll
  for (int a_=0;a_<8;a_++)
#pragma unroll
    for (int b_=0;b_<4;b_++) acc[a_][b_] = (f32x4){0.f,0.f,0.f,0.f};

  float scv[4], biv[4];
  if constexpr (DUAL){
#pragma unroll
    for (int nt=0;nt<4;nt++){
      const int colg = (wc<<6) + (nt<<4) + lm;
      scv[nt] = scale[colg]; biv[nt] = bias[colg];
    }
  }
  auto xf = [&](){                 // DUAL boundary transform (bn+lrelu on conv part)
#pragma unroll
    for (int mt=0;mt<8;mt++)
#pragma unroll
      for (int nt=0;nt<4;nt++)
#pragma unroll
        for (int r=0;r<4;r++){
          float v = acc[mt][nt][r]*scv[nt] + biv[nt];
          acc[mt][nt][r] = lrelu_f(v);
        }
  };

  // stage one A quarter-pair unit (16KiB, 2 gll/thread) of K-tile tau
  auto stA = [&](int tau, int odd){
    u16* dbase = &ldsA[tau & 1][0];
#pragma unroll
    for (int u=0; u<2; u++){
      const int riu = (wv<<4) + (u<<3);                       // 0..120, wave-uniform
      const int rl  = riu + (odd<<6) + ((riu >= 64) ? 64 : 0);// LDS/global row base
      u16* dst = dbase + (rl<<6);
      if (tau < t1){
        const int kloc = tau << 6;
        const u16* src = baA1 + (long)rl*Arow1 + kloc;
        if (!interior){
          const int tap = (kloc + cG*8) >> lgCin1;
          const int pos = posL + rl*S1 + tap;
          if ((u32)pos >= (u32)Lin1) src = zb;                // per-lane zero-page clamp
        }
        gll16(src, dst);
      } else {
        const int kloc = (tau << 6) - K1;                     // identity path: never OOB
        gll16(baA2 + (long)rl*Arow2 + kloc, dst);
      }
    }
  };
  // stage one B quarter-pair unit
  auto stB = [&](int tau, int odd){
    u16* dbase = &ldsB[tau & 1][0];
#pragma unroll
    for (int u=0; u<2; u++){
      const int riu = (wv<<4) + (u<<3);
      const int cl  = (riu & 31) + ((riu >> 5) << 6) + (odd << 5);
      u16* dst = dbase + (cl<<6);
      if (tau < t1) gll16(baB1 + (long)cl*K1 + (tau<<6), dst);
      else          gll16(baB2 + (long)cl*K2 + ((tau<<6) - K1), dst);
    }
  };

  short8 Ar[4][2], Br0[2][2], Br1[2][2];

  // prologue: tiles 0 and 1 fully staged -> vmcnt(8) = tile0 landed (tile1 in flight)
  stA(0,0); stA(0,1); stB(0,0); stB(0,1);
  if (nT > 1){ stA(1,0); stA(1,1); stB(1,0); stB(1,1); }
  VMW(8); SBAR();

  for (int g2 = 0; g2 < nT; g2 += 2){     // nT even
    KTILE(g2,   0);
    KTILE(g2+1, 1);
  }
  asm volatile("s_waitcnt vmcnt(0)" ::: "memory");

  // epilogue (Cout==256): non-DUAL applies bn+lrelu; DUAL acc already final
#pragma unroll
  for (int nt=0; nt<4; nt++){
    const int colg = (wc<<6) + (nt<<4) + lm;
    float sc = 1.0f, bi = 0.0f;
    if constexpr (!DUAL){ sc = scale[colg]; bi = bias[colg]; }
#pragma unroll
    for (int mt=0; mt<8; mt++){
#pragma unroll
      for (int r=0; r<4; r++){
        const long pm = (long)pm0 + (wr<<7) + (mt<<4) + (lq<<2) + r;
        float v = acc[mt][nt][r];
        if constexpr (!DUAL) v = lrelu_f(v*sc + bi);
        Out[pm*256 + colg] = f2bf(v);
      }
    }
  }
}

#undef RDA
#undef RDB
#undef MME
#undef KTILE

// --------------------------- prep kernels (fp32 -> bf16) --------------------
__global__ void bnfold_kernel(
    const float* __restrict__ bn0, const float* __restrict__ rbn1, const float* __restrict__ rbn2,
    float* s0, float* b0, float* s1, float* b1, float* s2, float* b2)
{
  const int blk = blockIdx.x, t = threadIdx.x;   // t < 256
  const float* p; float *so, *bo;
  if (blk == 0){ p = bn0; so = s0; bo = b0; }
  else if (blk <= 5){ int i = blk-1; p = rbn1 + i*1024; so = s1+i*256; bo = b1+i*256; }
  else { int i = blk-6; p = rbn2 + i*1024; so = s2+i*256; bo = b2+i*256; }
  const float g = p[t], be = p[256+t], m = p[512+t], v = p[768+t];
  const float sc = g / sqrtf(v + 1e-5f);
  so[t] = sc; bo[t] = be - m*sc;
}

__global__ void w0prep_kernel(const float* __restrict__ cw, u16* __restrict__ w0p){
  const int co = blockIdx.x, k = threadIdx.x;
  const int tp = k >> 4, ci = k & 15;
  u16 v = 0;
  if (tp < 15 && ci < 12) v = f2bf(cw[(co*12 + ci)*15 + tp]);
  w0p[co*256 + k] = v;
}

// coalesced: threads walk the 2304-elem source row contiguously
__global__ void wrprep_kernel(const float* __restrict__ c1, const float* __restrict__ c2, u16* __restrict__ wr){
  const int co = blockIdx.x, slot = blockIdx.y;
  const float* src = (slot < 5) ? (c1 + (size_t)slot*589824 + (size_t)co*2304)
                                : (c2 + (size_t)(slot-5)*589824 + (size_t)co*2304);
  u16* dst = wr + (size_t)slot*589824 + (size_t)co*2304;
  for (int k = threadIdx.x; k < 2304; k += 256){
    const int ci = k/9, tp = k - ci*9;
    dst[tp*256 + ci] = f2bf(src[k]);
  }
}

__global__ void widprep_kernel(const float* __restrict__ idw, u16* __restrict__ wid){
  const int co = blockIdx.x, sl = blockIdx.y, ci = threadIdx.x;
  u16 h = f2bf(0.5f * idw[((size_t)sl*256 + co)*256 + ci]);
  u16* dst = wid + (size_t)sl*131072 + co*512;
  dst[ci] = h; dst[256 + ci] = h;
}

__global__ void x16prep_kernel(const float* __restrict__ x, u16* __restrict__ x16){
  const int p = blockIdx.x*256 + threadIdx.x;
  const int b = blockIdx.y;
  u16 v[16];
#pragma unroll
  for (int ci=0; ci<16; ci++) v[ci] = (ci < 12) ? f2bf(x[((size_t)(b*12+ci))*4096 + p]) : (u16)0;
  uint4 A4, B4;
  A4.x = v[0] | ((u32)v[1]<<16); A4.y = v[2] | ((u32)v[3]<<16);
  A4.z = v[4] | ((u32)v[5]<<16); A4.w = v[6] | ((u32)v[7]<<16);
  B4.x = v[8] | ((u32)v[9]<<16); B4.y = v[10]| ((u32)v[11]<<16);
  B4.z = v[12]| ((u32)v[13]<<16); B4.w = v[14]| ((u32)v[15]<<16);
  uint4* dst = (uint4*)&x16[((size_t)b*4096 + p)*16];
  dst[0] = A4; dst[1] = B4;
}

// generic fp32 -> bf16 cast
__global__ void castb_kernel(const float* __restrict__ src, u16* __restrict__ dst, int n){
  const int i = blockIdx.x*256 + threadIdx.x;
  if (i < n) dst[i] = f2bf(src[i]);
}

__global__ void zerok_kernel(u16* __restrict__ zb){ zb[threadIdx.x] = 0; }

__global__ void canary_kernel(float* __restrict__ outp){
  const int idx = blockIdx.x*256 + threadIdx.x;
  if (idx < 3456) outp[idx] = 131072.0f;
}

// --------------------------- fp32 kernels -----------------------------------
// r18: fused lead-II branch. One kernel does BOTH convs (flut k=15 s=2 p=7,
// pvc k=9 s=2 p=4) + bn + lrelu + both max-pools, never materializing the
// (64,64,2048) activations (saves ~134 MB of fp32 traffic + 3 launches).
__global__ __launch_bounds__(256) void leadii_fused(
    const float* __restrict__ x,
    const float* __restrict__ fwg, const float* __restrict__ fbc, const float* __restrict__ fbn,
    const float* __restrict__ pwg, const float* __restrict__ pbc, const float* __restrict__ pbn,
    float* __restrict__ fp, float* __restrict__ pp)
{
  __shared__ float ldin[1040];
  const int opart = blockIdx.x;            // output chunk [opart*512, +512)
  const int z     = blockIdx.y;
  const int t = threadIdx.x;
  const float* xrow = x + ((size_t)(z*12 + 1))*4096;
  const int lo_in = opart*1024 - 7;        // ldin[i] = xrow[lo_in + i]
  for (int i = t; i < 1037; i += 256){
    const int pos = lo_in + i;
    ldin[i] = ((u32)pos < 4096u) ? xrow[pos] : 0.f;
  }
  __syncthreads();
  const int q = t >> 6, c = t & 63;
  float fw[15], pw[9];
#pragma unroll
  for (int k = 0; k < 15; k++) fw[k] = fwg[c*15 + k];
#pragma unroll
  for (int k = 0; k < 9;  k++) pw[k] = pwg[c*9 + k];
  const float fsc = fbn[c] / sqrtf(fbn[192+c] + 1e-5f);
  const float fsh = fbn[64+c] - fbn[128+c]*fsc;
  const float psc = pbn[c] / sqrtf(pbn[192+c] + 1e-5f);
  const float psh = pbn[64+c] - pbn[128+c]*psc;
  const float cbf = fbc[c], cbp = pbc[c];
  const int ob = q*128;                    // local output base for this thread
#pragma unroll
  for (int jp = 0; jp < 2; jp++){
    float pmx = -1e30f;
#pragma unroll
    for (int jf = 0; jf < 2; jf++){
      float fmx = -1e30f;
      for (int kk = 0; kk < 32; kk++){
        const int o = ob + jp*64 + jf*32 + kk;
        const float* s = &ldin[2*o];       // flut taps s[0..14]; pvc taps s[3..11]
        float fa = cbf;
#pragma unroll
        for (int k = 0; k < 15; k++) fa += fw[k]*s[k];
        fmx = fmaxf(fmx, lrelu_f(fa*fsc + fsh));
        float pa = cbp;
#pragma unroll
        for (int k = 0; k < 9;  k++) pa += pw[k]*s[3+k];
        pmx = fmaxf(pmx, lrelu_f(pa*psc + psh));
      }
      fp[(size_t)z*4096 + c*64 + opart*16 + q*4 + jp*2 + jf] = fmx;
    }
    pp[(size_t)z*2048 + c*32 + opart*8 + q*2 + jp] = pmx;
  }
}

// attention v3: one wave per (sample, head); K,V staged in LDS.
// qkv rows (64*nb, 768) fp32 -> o (64*nb, 256) bf16
__global__ __launch_bounds__(64) void attn3(const float* __restrict__ qkv, u16* __restrict__ o){
  const int bh = blockIdx.x;
  const int b = bh >> 3, h = bh & 7;
  __shared__ float Ks[2048], Vs[2048];
  const int t = threadIdx.x;
  for (int e = t; e < 2048; e += 64){
    const int r = e >> 5, c = e & 31;
    const size_t base = ((size_t)(b*64 + r))*768 + h*32 + c;
    Ks[e] = qkv[base + 256];
    Vs[e] = qkv[base + 512];
  }
  __syncthreads();
  float qv[32];
  const float* qp = qkv + ((size_t)(b*64 + t))*768 + h*32;
#pragma unroll
  for (int d = 0; d < 32; d++) qv[d] = qp[d];
  float s[64]; float mx = -1e30f;
  const float isq = 0.17677669529663687f;        // 1/sqrt(32)
  for (int kc = 0; kc < 64; kc++){
    const float* kr = &Ks[kc*32];
    float dot = 0.f;
#pragma unroll
    for (int d = 0; d < 32; d++) dot += qv[d]*kr[d];
    dot *= isq; s[kc] = dot; mx = fmaxf(mx, dot);
  }
  float sum = 0.f;
  for (int kc = 0; kc < 64; kc++){ float e = __expf(s[kc]-mx); s[kc] = e; sum += e; }
  const float inv = 1.0f/sum;
  float ov[32];
#pragma unroll
  for (int d = 0; d < 32; d++) ov[d] = 0.f;
  for (int kc = 0; kc < 64; kc++){
    const float* vr = &Vs[kc*32];
    const float wgt = s[kc];
#pragma unroll
    for (int d = 0; d < 32; d++) ov[d] += wgt*vr[d];
  }
  u16* op = o + ((size_t)(b*64 + t))*256 + h*32;
#pragma unroll
  for (int d = 0; d < 32; d++) op[d] = f2bf(ov[d]*inv);
}

__global__ void xmain_s(const float* __restrict__ om, float* __restrict__ xm, int b0){
  const int e = threadIdx.x, bl = blockIdx.x;
  float m = -1e30f;
  for (int s = 0; s < 64; s++) m = fmaxf(m, om[((size_t)(bl*64+s))*256 + e]);
  xm[(size_t)(b0+bl)*256 + e] = m;
}

// FC dot-product: one block per output scalar (b,j); float4 K-reduction.
template<int N, int K>
__global__ __launch_bounds__(256) void fcdot_kernel(const float* __restrict__ inp,
    const float* __restrict__ w, float* __restrict__ outp)
{
  const int b = blockIdx.x, j = blockIdx.y;
  const int t = threadIdx.x;
  const float4* x4 = (const float4*)(inp + (size_t)b*K);
  const float4* w4 = (const float4*)(w   + (size_t)j*K);
  float s = 0.f;
#pragma unroll
  for (int k = t; k < K/4; k += 256){
    const float4 a = x4[k], c = w4[k];
    s += a.x*c.x + a.y*c.y + a.z*c.z + a.w*c.w;
  }
  for (int o2 = 32; o2 > 0; o2 >>= 1) s += __shfl_down(s, o2, 64);
  __shared__ float red[4];
  const int wv = t >> 6, lane = t & 63;
  if (lane == 0) red[wv] = s;
  __syncthreads();
  if (t == 0) outp[(size_t)b*N + j] = lrelu_f(red[0]+red[1]+red[2]+red[3]);
}

// r18 DFT v2: block = (b, 8-bin chunk); row staged once in LDS; 8 lanes/bin
// with interleaved n-assignment (n = k*8+sub -> conflict-free, 8-way bcast);
// twiddle rotation recurrence; shfl_xor reduce within 8-lane groups.
__global__ __launch_bounds__(256) void fft2_kernel(const float* __restrict__ x, float* __restrict__ mag){
  __shared__ float row[4096];
  const int b = blockIdx.x, chunk = blockIdx.y;
  const int t = threadIdx.x;
  const float* xp = x + ((size_t)(b*12 + 1))*4096;
  for (int i = t; i < 4096; i += 256) row[i] = xp[i];
  __syncthreads();
  const int binl = t >> 3, sub = t & 7;
  const int bin = chunk*32 + binl + 50;
  const float C = 6.283185307179586f/4096.0f;
  float cr, si;  __sincosf((float)((bin*sub) & 4095)*C, &si, &cr);
  float cS, sS;  __sincosf((float)((bin*8)   & 4095)*C, &sS, &cS);
  float re = 0.f, im = 0.f;
  for (int k = 0; k < 512; k++){
    const float xv = row[(k<<3) + sub];
    re += xv*cr; im += xv*si;
    const float c2 = cr*cS - si*sS;
    si = cr*sS + si*cS;
    cr = c2;
  }
  re += __shfl_xor(re, 1, 8); im += __shfl_xor(im, 1, 8);
  re += __shfl_xor(re, 2, 8); im += __shfl_xor(im, 2, 8);
  re += __shfl_xor(re, 4, 8); im += __shfl_xor(im, 4, 8);
  if (sub == 0) mag[b*256 + chunk*32 + binl] = sqrtf(re*re + im*im);
}

__global__ void rowmax_kernel(const float* __restrict__ mag, float* __restrict__ rmax){
  const int b = blockIdx.x, t = threadIdx.x;
  __shared__ float r[256];
  r[t] = mag[b*256 + t]; __syncthreads();
  for (int o2 = 128; o2 > 0; o2 >>= 1){ if (t < o2) r[t] = fmaxf(r[t], r[t+o2]); __syncthreads(); }
  if (t == 0) rmax[b] = r[0];
}

__global__ void freq_kernel(const float* __restrict__ mag, const float* __restrict__ rmax,
                            const float* __restrict__ fw, const float* __restrict__ fb,
                            float* __restrict__ outp){
  const int b = blockIdx.x, j = threadIdx.x;  // 32
  const float mx = rmax[b];
  const float sc = mx > 0.f ? 1.0f/mx : 1.0f;
  float acc = fb[j];
  for (int i = 0; i < 256; i++) acc += (mag[b*256+i]*sc) * fw[(size_t)j*256 + i];
  outp[b*32 + j] = lrelu_f(acc);
}

__global__ void final_kernel(const float* __restrict__ xm, const float* __restrict__ l,
                             const float* __restrict__ fr, const float* __restrict__ fv,
                             const float* __restrict__ pv, const float* __restrict__ fcw,
                             const float* __restrict__ fcb, float* __restrict__ outp){
  const int b = blockIdx.x, j = threadIdx.x;  // 32 threads, 27 active
  if (j >= 27) return;
  float acc = fcb[j];
  const float* wr_ = fcw + (size_t)j*396;
  for (int i = 0; i < 256; i++) acc += xm[b*256+i] * wr_[i];
  for (int i = 0; i < 12;  i++) acc += l[b*12+i]   * wr_[256+i];
  for (int i = 0; i < 32;  i++) acc += fr[b*32+i]  * wr_[268+i];
  for (int i = 0; i < 64;  i++) acc += fv[b*64+i]  * wr_[300+i];
  for (int i = 0; i < 32;  i++) acc += pv[b*32+i]  * wr_[364+i];
  outp[b*27 + j] = acc;
  outp[64*27 + b*27 + j] = 1.0f/(1.0f + __expf(-acc));
}

// --------------------------- host side --------------------------------------
extern "C" void kernel_launch(void* const* d_in, const int* in_sizes, int n_in,
                              void* d_out, int out_size, void* d_ws, size_t ws_size,
                              hipStream_t stream)
{
  const float* x       = (const float*)d_in[0];
  const float* l       = (const float*)d_in[1];
  const float* conv_w  = (const float*)d_in[2];
  const float* bn0     = (const float*)d_in[3];
  const float* rb_c1   = (const float*)d_in[4];
  const float* rb_bn1  = (const float*)d_in[5];
  const float* rb_c2   = (const float*)d_in[6];
  const float* rb_bn2  = (const float*)d_in[7];
  const float* rb_id   = (const float*)d_in[8];
  const float* in_w    = (const float*)d_in[9];
  const float* in_b    = (const float*)d_in[10];
  const float* out_w   = (const float*)d_in[11];
  const float* out_b   = (const float*)d_in[12];
  const float* flut_w  = (const float*)d_in[13];
  const float* flut_b  = (const float*)d_in[14];
  const float* flut_bn = (const float*)d_in[15];
  const float* pvc_w   = (const float*)d_in[16];
  const float* pvc_b   = (const float*)d_in[17];
  const float* pvc_bn  = (const float*)d_in[18];
  const float* w_flut2 = (const float*)d_in[19];
  const float* w_pvc2  = (const float*)d_in[20];
  const float* freq_w  = (const float*)d_in[21];
  const float* freq_b  = (const float*)d_in[22];
  const float* fc_w    = (const float*)d_in[23];
  const float* fc_b    = (const float*)d_in[24];
  float* outp = (float*)d_out;

  char* ws = (char*)d_ws;
  size_t off = 0;
  auto alloc = [&](size_t bytes)->char*{ char* p = ws + off; off = (off + bytes + 255) & ~(size_t)255; return p; };

  // ---- persistent (~16.7 MiB) ----
  u16* wr    = (u16*)alloc((size_t)10*589824*2);   // 11.25 MiB res weights [slot][co][tap*256+ci]
  u16* wid   = (u16*)alloc((size_t)5*131072*2);    //  1.25 MiB identity 2-tap weights
  u16* w0p   = (u16*)alloc(131072);                //  conv0 weights, K-padded
  u16* wqkvb = (u16*)alloc(196608*2);              //  qkv proj weights bf16 (768,256)
  u16* woutb = (u16*)alloc(65536*2);               //  out proj weights bf16 (256,256)
  u16* h5b   = (u16*)alloc((size_t)64*64*256*2);   //  2 MiB (B*64,256) bf16
  u16* zbuf  = (u16*)alloc(256);                   //  16B+ zero page for OOB-tap clamp
  float* s0 = (float*)alloc(1024);  float* b0 = (float*)alloc(1024);
  float* s1 = (float*)alloc(5120);  float* b1 = (float*)alloc(5120);
  float* s2 = (float*)alloc(5120);  float* b2 = (float*)alloc(5120);
  float* xm    = (float*)alloc(65536);
  float* fpool = (float*)alloc((size_t)64*4096*4); // 1 MiB
  float* ppool = (float*)alloc((size_t)64*2048*4); // 0.5 MiB
  float* mag   = (float*)alloc(65536);
  float* rmax  = (float*)alloc(1024);
  float* fvecv = (float*)alloc(16384);
  float* pvecv = (float*)alloc(8192);
  float* freqv = (float*)alloc(8192);

  // ---- adaptive batch slice: chain arena = 2.625*sp MiB (bf16 activations) ----
  const size_t rem = (ws_size > off) ? (ws_size - off) : 0;
  int sp = 0;
  for (int c = 64; c >= 2; c >>= 1)
    if ((size_t)c*2752512 + (1<<20) <= rem){ sp = c; break; }
  if (sp == 0){ canary_kernel<<<14,256,0,stream>>>(outp); return; }

  u16* x16q = (u16*)alloc((size_t)sp*131072);      // (sp,4096,16) bf16
  u16* h0q  = (u16*)alloc((size_t)sp*1048576);     // (sp,2048,256) bf16
  u16* hCq  = (u16*)alloc((size_t)sp*524288);      // (sp,<=1024,256) bf16
  u16* ping = (u16*)alloc((size_t)sp*524288);
  u16* pong = (u16*)alloc((size_t)sp*524288);

  // ---- param prep (once) ----
  zerok_kernel<<<1,128,0,stream>>>(zbuf);
  bnfold_kernel<<<11,256,0,stream>>>(bn0, rb_bn1, rb_bn2, s0,b0,s1,b1,s2,b2);
  w0prep_kernel<<<256,256,0,stream>>>(conv_w, w0p);
  wrprep_kernel<<<dim3(256,10),256,0,stream>>>(rb_c1, rb_c2, wr);
  widprep_kernel<<<dim3(256,5),256,0,stream>>>(rb_id, wid);
  castb_kernel<<<768,256,0,stream>>>(in_w, wqkvb, 196608);
  castb_kernel<<<256,256,0,stream>>>(out_w, woutb, 65536);

  // ---- res chain: conv0 on gemm_conv; i=0 on gemm8; i>=1 on gemm_sm
  //      (r26: 64-row tiles, 4 blk/CU — occupancy mechanism proven at i>=2) ----
  for (int s = 0; s < 64/sp; s++){
    const float* xs = x + (size_t)s*sp*49152;
    x16prep_kernel<<<dim3(16,sp),256,0,stream>>>(xs, x16q);
    // conv0: (sp,4096,16) -> (sp,2048,256), k=15 s=2 p=7, K padded to 256
    {
      const int mm = sp*16, nn = 2;
      gemm_conv<true,false,false><<<mm*nn,256,0,stream>>>(
          x16q - 112, w0p, nullptr, nullptr, h0q, s0, b0,
          256, 0, 11, 2, 4, 7, 4096, 65536, 32, 0, 0, 256, 256, 1, mm, nn);
    }
    int Lin = 2048;
    const u16* bin = h0q;
    for (int i = 0; i < 5; i++){
      const int Lo = Lin >> 1;
      const int lgLo = 10 - i;
      if (i < 1){
        // 8-phase 256x256 path (grid 256 blocks = 1 block/CU at sp=64)
        const int mb = sp*Lo/256;
        gemm8<false><<<mb,512,0,stream>>>(
            bin - 1024, wr + (size_t)i*589824, nullptr, nullptr, hCq, s1+i*256, b1+i*256, zbuf,
            2304, 0, lgLo, 2, 8, 4, Lin, Lin*256, 512, 0, 0);
        u16* bout = (i&1) ? pong : ping;
        gemm8<true><<<mb,512,0,stream>>>(
            hCq - 1024, wr + (size_t)(5+i)*589824, bin, wid + (size_t)i*131072,
            bout, s2+i*256, b2+i*256, zbuf,
            2304, 512, lgLo, 1, 8, 4, Lo, Lo*256, 256, Lin*256, 512);
        bin = bout;
      } else {
        // i>=1: 64x128 tiles (r24/r26) — more blocks/CU hides latency
        const int mm = sp*Lo/64, nn = 2;
        gemm_sm<true,false,false><<<mm*nn,256,0,stream>>>(
            bin - 1024, wr + (size_t)i*589824, nullptr, nullptr, hCq, s1+i*256, b1+i*256,
            2304, 0, lgLo, 2, 8, 4, Lin, Lin*256, 512, 0, 0, 256, 256, 1, mm, nn);
        if (i < 4){
          u16* bout = (i&1) ? pong : ping;
          gemm_sm<true,true,false><<<mm*nn,256,0,stream>>>(
              hCq - 1024, wr + (size_t)(5+i)*589824, bin, wid + (size_t)i*131072,
              bout, s2+i*256, b2+i*256,
              2304, 512, lgLo, 1, 8, 4, Lo, Lo*256, 256, Lin*256, 512, 256, 256, 1, mm, nn);
          bin = bout;
        } else {
          gemm_sm<true,true,false><<<mm*nn,256,0,stream>>>(
              hCq - 1024, wr + (size_t)(5+i)*589824, bin, wid + (size_t)i*131072,
              h5b + (size_t)s*sp*16384, s2+i*256, b2+i*256,
              2304, 512, lgLo, 1, 8, 4, Lo, Lo*256, 256, Lin*256, 512, 256, 256, 1, mm, nn);
        }
      }
      Lin = Lo;
    }
  }

  // ---- MHA on MFMA GEMMs; slice if arena is small ----
  {
    const int nsl = (sp >= 8) ? 1 : 4;
    const int rows = 4096/nsl;                       // 64*samples per slice
    float* qkvF = (float*)x16q;                      // arena aliases (chain is dead)
    u16*   o_b  = (u16*)(qkvF + (size_t)rows*768);
    float* omF  = (float*)(o_b + (size_t)rows*256);
    for (int s = 0; s < nsl; s++){
      const int mm = rows/128;
      gemm_conv<false,false,true><<<mm*6,256,0,stream>>>(
          h5b + (size_t)s*rows*256, wqkvb, nullptr, nullptr, qkvF, nullptr, in_b,
          256, 0, 12, 1, 8, 0, 0, 0, 256, 0, 0, 768, 768, 0, mm, 6);
      attn3<<<(rows/64)*8,64,0,stream>>>(qkvF, o_b);
      gemm_conv<false,false,true><<<mm*2,256,0,stream>>>(
          o_b, woutb, nullptr, nullptr, omF, nullptr, out_b,
          256, 0, 12, 1, 8, 0, 0, 0, 256, 0, 0, 256, 256, 0, mm, 2);
      xmain_s<<<rows/64,256,0,stream>>>(omF, xm, s*(rows/64));
    }
  }

  // ---- lead_II branch: single fused kernel (conv+bn+lrelu+pool x2) ----
  leadii_fused<<<dim3(4,64),256,0,stream>>>(x, flut_w, flut_b, flut_bn,
                                            pvc_w, pvc_b, pvc_bn, fpool, ppool);
  fcdot_kernel<64,4096><<<dim3(64,64),256,0,stream>>>(fpool, w_flut2, fvecv);
  fcdot_kernel<32,2048><<<dim3(64,32),256,0,stream>>>(ppool, w_pvc2, pvecv);

  // ---- FFT branch (LDS-staged DFT) ----
  fft2_kernel<<<dim3(64,8),256,0,stream>>>(x, mag);
  rowmax_kernel<<<64,256,0,stream>>>(mag, rmax);
  freq_kernel<<<64,32,0,stream>>>(mag, rmax, freq_w, freq_b, freqv);

  // ---- combine + logits + sigmoid ----
  final_kernel<<<64,32,0,stream>>>(xm, l, freqv, fvecv, pvecv, fc_w, fc_b, outp);
  (void)in_sizes; (void)n_in; (void)out_size;
}